// Round 6
// baseline (315.565 us; speedup 1.0000x reference)
//
#include <hip/hip_runtime.h>
#include <cstddef>

typedef __bf16 bf16x8 __attribute__((ext_vector_type(8)));
typedef float  f32x4  __attribute__((ext_vector_type(4)));
typedef unsigned short u16x8 __attribute__((ext_vector_type(8)));

#define GLOBAL_AS __attribute__((address_space(1)))
#define LDS_AS    __attribute__((address_space(3)))

__device__ __forceinline__ void gload_lds16(const void* g, void* l) {
    __builtin_amdgcn_global_load_lds((const GLOBAL_AS unsigned int*)g,
                                     (LDS_AS unsigned int*)l, 16, 0, 0);
}

__device__ __forceinline__ unsigned short f2bf(float f) {
    union { float f; unsigned int u; } v; v.f = f;
    unsigned int r = v.u + 0x7FFFu + ((v.u >> 16) & 1u);   // RNE
    return (unsigned short)(r >> 16);
}
__device__ __forceinline__ float bf2f(unsigned short h) {
    union { unsigned int u; float f; } v; v.u = ((unsigned int)h) << 16;
    return v.f;
}

// ---------------------------------------------------------------------------
// Transpose + cast (expert_W): src [batch][R][C] f32 -> dst [batch][C][R] bf16
// ---------------------------------------------------------------------------
__global__ __launch_bounds__(256) void transpose_cast_kernel(
    const float* __restrict__ src, unsigned short* __restrict__ dst,
    int R, int C)
{
    const int bat = blockIdx.z;
    src += (size_t)bat * R * C;
    dst += (size_t)bat * R * C;
    const int r0 = blockIdx.y * 64, c0 = blockIdx.x * 64;
    __shared__ float t[64][65];
    const int tid = threadIdx.x;
    const int rr = tid >> 4;
    const int cc = (tid & 15) * 4;

    #pragma unroll
    for (int p = 0; p < 4; p++) {
        int r = p * 16 + rr;
        const float4 v = *reinterpret_cast<const float4*>(&src[(size_t)(r0 + r) * C + c0 + cc]);
        t[r][cc + 0] = v.x; t[r][cc + 1] = v.y; t[r][cc + 2] = v.z; t[r][cc + 3] = v.w;
    }
    __syncthreads();
    #pragma unroll
    for (int p = 0; p < 4; p++) {
        int c = p * 16 + rr;
        ushort4 o;
        o.x = f2bf(t[cc + 0][c]); o.y = f2bf(t[cc + 1][c]);
        o.z = f2bf(t[cc + 2][c]); o.w = f2bf(t[cc + 3][c]);
        *reinterpret_cast<ushort4*>(&dst[(size_t)(c0 + c) * R + r0 + cc]) = o;
    }
}

// ---------------------------------------------------------------------------
// x transpose + fused gate partial-logits.
// ---------------------------------------------------------------------------
__global__ __launch_bounds__(256) void transpose_x_gate_kernel(
    const float* __restrict__ src, const float* __restrict__ gW,
    unsigned short* __restrict__ dst, float* __restrict__ plog)
{
    const int bat = blockIdx.z;
    const int R = 1024, C = 512;
    const float* srcb = src + (size_t)bat * R * C;
    unsigned short* dstb = dst + (size_t)bat * R * C;
    const int r0 = blockIdx.y * 64, c0 = blockIdx.x * 64;
    __shared__ float t[64][65];
    __shared__ float gWs[64][8];
    __shared__ float pacc[4][64][9];
    const int tid = threadIdx.x;
    const int rr = tid >> 4;
    const int cc = (tid & 15) * 4;

    if (tid < 128) {
        reinterpret_cast<float4*>(&gWs[0][0])[tid] =
            reinterpret_cast<const float4*>(gW + (size_t)r0 * 8)[tid];
    }
    #pragma unroll
    for (int p = 0; p < 4; p++) {
        int r = p * 16 + rr;
        const float4 v = *reinterpret_cast<const float4*>(&srcb[(size_t)(r0 + r) * C + c0 + cc]);
        t[r][cc + 0] = v.x; t[r][cc + 1] = v.y; t[r][cc + 2] = v.z; t[r][cc + 3] = v.w;
    }
    __syncthreads();
    #pragma unroll
    for (int p = 0; p < 4; p++) {
        int c = p * 16 + rr;
        ushort4 o;
        o.x = f2bf(t[cc + 0][c]); o.y = f2bf(t[cc + 1][c]);
        o.z = f2bf(t[cc + 2][c]); o.w = f2bf(t[cc + 3][c]);
        *reinterpret_cast<ushort4*>(&dstb[(size_t)(c0 + c) * R + r0 + cc]) = o;
    }

    {
        const int nl = tid & 63;
        const int sc = tid >> 6;
        float a[8];
        #pragma unroll
        for (int e = 0; e < 8; e++) a[e] = 0.f;
        for (int s = sc * 16; s < sc * 16 + 16; s++) {
            float xv = t[s][nl];
            #pragma unroll
            for (int e = 0; e < 8; e++) a[e] = fmaf(xv, gWs[s][e], a[e]);
        }
        #pragma unroll
        for (int e = 0; e < 8; e++) pacc[sc][nl][e] = a[e];
        __syncthreads();
        if (tid < 64) {
            const size_t base = (((size_t)bat * 16 + blockIdx.y) * 512 + c0 + tid) * 8;
            #pragma unroll
            for (int e = 0; e < 8; e++) {
                float v = ((pacc[0][tid][e] + pacc[1][tid][e]) + pacc[2][tid][e]) + pacc[3][tid][e];
                plog[base + e] = v;
            }
        }
    }
}

// ---------------------------------------------------------------------------
// Gate stage 2: reduce partials (fixed order), softmax, top-2, histogram.
// ---------------------------------------------------------------------------
__global__ __launch_bounds__(256) void gate_stage2_kernel(
    const float* __restrict__ plog,
    float* __restrict__ gate, int* __restrict__ e01,
    float* __restrict__ w0a, float* __restrict__ w1a,
    int* __restrict__ hist)
{
    __shared__ int h[16];
    const int tid = threadIdx.x;
    if (tid < 16) h[tid] = 0;
    __syncthreads();

    const int t = blockIdx.x * 256 + tid;
    const int b = t >> 9;
    const int n = t & 511;

    float acc[8];
    #pragma unroll
    for (int e = 0; e < 8; e++) acc[e] = 0.f;
    for (int y = 0; y < 16; y++) {
        const float* pp = plog + (((size_t)b * 16 + y) * 512 + n) * 8;
        const float4 lo = *reinterpret_cast<const float4*>(pp);
        const float4 hi = *reinterpret_cast<const float4*>(pp + 4);
        acc[0] += lo.x; acc[1] += lo.y; acc[2] += lo.z; acc[3] += lo.w;
        acc[4] += hi.x; acc[5] += hi.y; acc[6] += hi.z; acc[7] += hi.w;
    }
    float m = acc[0];
    #pragma unroll
    for (int e = 1; e < 8; e++) m = fmaxf(m, acc[e]);
    float p[8], s = 0.f;
    #pragma unroll
    for (int e = 0; e < 8; e++) { p[e] = __expf(acc[e] - m); s += p[e]; }
    float inv = 1.f / s;
    #pragma unroll
    for (int e = 0; e < 8; e++) p[e] *= inv;

    int e0 = 0;
    #pragma unroll
    for (int e = 1; e < 8; e++) if (p[e] > p[e0]) e0 = e;
    int e1 = -1;
    #pragma unroll
    for (int e = 0; e < 8; e++) {
        if (e == e0) continue;
        if (e1 < 0 || p[e] > p[e1]) e1 = e;
    }

    const size_t base = (size_t)t * 8;
    #pragma unroll
    for (int e = 0; e < 8; e++) gate[base + e] = p[e];
    e01[t] = e0 | (e1 << 8);
    w0a[t] = p[e0];
    w1a[t] = p[e1];

    atomicAdd(&h[e0], 1);
    atomicAdd(&h[8 + e1], 1);
    __syncthreads();
    if (tid < 16) hist[blockIdx.x * 16 + tid] = h[tid];
}

__global__ __launch_bounds__(256) void gate_mean_kernel(
    const float* __restrict__ gate, float* __restrict__ out)
{
    const int idx = blockIdx.x * 256 + threadIdx.x;
    float s = 0.f;
    #pragma unroll 8
    for (int b = 0; b < 64; b++) s += gate[(size_t)b * 4096 + idx];
    out[idx] = s * (1.f / 64.f);
}

// ---------------------------------------------------------------------------
// Scan: hist[128][16] -> chunk_off, meta { base[16], cnt[16], tile_scan[17] }
// tile granularity = 256 tokens.
// ---------------------------------------------------------------------------
__global__ __launch_bounds__(256) void scan_kernel(
    const int* __restrict__ hist, int* __restrict__ chunk_off,
    int* __restrict__ meta)
{
    __shared__ int cnt_s[16];
    const int tid = threadIdx.x;
    if (tid < 16) {
        int run = 0;
        for (int c = 0; c < 128; c++) {
            chunk_off[c * 16 + tid] = run;
            run += hist[c * 16 + tid];
        }
        cnt_s[tid] = run;
        meta[16 + tid] = run;
    }
    __syncthreads();
    __shared__ int base_s[16];
    if (tid == 0) {
        int run = 0, trun = 0;
        meta[32] = 0;
        for (int g = 0; g < 16; g++) {
            base_s[g] = run;
            meta[g] = run;
            run += cnt_s[g];
            trun += (cnt_s[g] + 255) >> 8;      // 256-token tiles
            meta[33 + g] = trun;
        }
    }
    __syncthreads();
    for (int i = tid; i < 2048; i += 256)
        chunk_off[i] += base_s[i & 15];
}

// ---------------------------------------------------------------------------
// Fill: stable counting-sort placement, ballot-based ranking (no serial loop).
// ---------------------------------------------------------------------------
__global__ __launch_bounds__(256) void fill_kernel(
    const int* __restrict__ e01, const int* __restrict__ chunk_off,
    int* __restrict__ perm, int* __restrict__ posA, int* __restrict__ posB)
{
    __shared__ int wh[4][16];
    const int tid = threadIdx.x;
    const int wv = tid >> 6, lane = tid & 63;
    const int chunk = blockIdx.x;
    const int t = chunk * 256 + tid;
    const int ev = e01[t];
    const int e0 = ev & 255, e1 = ev >> 8;

    const unsigned long long ltmask = (lane == 63) ? 0x7FFFFFFFFFFFFFFFull
                                                   : ((1ull << lane) - 1ull);
    unsigned long long m0sel = 0, m1sel = 0;
    #pragma unroll
    for (int e = 0; e < 8; e++) {
        unsigned long long b0 = __ballot(e0 == e);
        unsigned long long b1 = __ballot(e1 == e);
        if (e0 == e) m0sel = b0;
        if (e1 == e) m1sel = b1;
        if (lane == 0) {
            wh[wv][e]     = __popcll(b0);
            wh[wv][8 + e] = __popcll(b1);
        }
    }
    const int r0l = __popcll(m0sel & ltmask);
    const int r1l = __popcll(m1sel & ltmask);
    __syncthreads();

    int off0 = 0, off1 = 0;
    for (int w = 0; w < wv; w++) { off0 += wh[w][e0]; off1 += wh[w][8 + e1]; }

    const int p0 = chunk_off[chunk * 16 + e0] + off0 + r0l;
    const int p1 = chunk_off[chunk * 16 + 8 + e1] + off1 + r1l;
    perm[p0] = t; perm[p1] = t;
    posA[t] = p0; posB[t] = p1;
}

// ---------------------------------------------------------------------------
// Grouped GEMM: 256x256x64 tile, 512 threads (8 waves, 2p x 4tok),
// 2-deep double buffer with COUNTED vmcnt (never drains to 0 mid-loop),
// raw s_barrier, chunk-XOR LDS swizzle (0 conflicts, r5-verified),
// XCD-aware 1D grid (34 token-tiles x 4 p-tiles per XCD).
// ---------------------------------------------------------------------------
__global__ __launch_bounds__(512, 2) void grouped_gemm_kernel(
    const unsigned short* __restrict__ Wt,      // [8][1024 p][1024 s]
    const unsigned short* __restrict__ xt,      // [32768 tok][1024 s]
    const int* __restrict__ perm,
    const int* __restrict__ meta,               // base[16],cnt[16],tile_scan[17]
    const float* __restrict__ expert_b,
    unsigned short* __restrict__ tmp)           // [65536][1024]
{
    const int d    = blockIdx.x;                // 0..1087
    const int xcd  = d & 7;
    const int jj   = d >> 3;                    // 0..135
    const int tile = xcd * 34 + (jj >> 2);      // 0..271
    const int p0   = (jj & 3) * 256;

    int g = -1;
    #pragma unroll
    for (int gg = 0; gg < 16; gg++) {
        if (tile >= meta[32 + gg] && tile < meta[33 + gg]) g = gg;
    }
    if (g < 0) return;                          // beyond last real tile
    const int lt = tile - meta[32 + g];
    const int e = g & 7;
    const int cnt_local = meta[16 + g] - lt * 256;
    const int pbase = meta[g] + lt * 256;

    __shared__ unsigned short As[2][256 * 64];  // 64 KB
    __shared__ unsigned short Bs[2][256 * 64];  // 64 KB

    const int tid  = threadIdx.x;
    const int wid  = tid >> 6, lane = tid & 63;
    const int wr = wid >> 2, wc = wid & 3;      // 2 (p) x 4 (tok)
    const int q = lane >> 4, r16 = lane & 15;

    const int srow   = tid >> 3;                // 0..63
    const int schunk = tid & 7;
    const int gcol   = (schunk ^ (srow & 7)) * 8;   // inverse-swizzled source col

    const unsigned short* Abase = Wt + (size_t)e * 1024 * 1024;

    int tok[4];
    #pragma unroll
    for (int c = 0; c < 4; c++) {
        int row = c * 64 + srow;
        int idx = row < cnt_local ? row : 0;
        tok[c] = perm[pbase + idx];
    }

    f32x4 acc[8][4];
    #pragma unroll
    for (int m = 0; m < 8; m++)
        #pragma unroll
        for (int nn = 0; nn < 4; nn++)
            acc[m][nn] = (f32x4){0.f, 0.f, 0.f, 0.f};

    // stage K-tile kt (A 256x64 + B 256x64) into buffer buf: 8 loads/thread
    #define STAGE(buf, kt) do {                                                   \
        _Pragma("unroll")                                                         \
        for (int c = 0; c < 4; c++) {                                             \
            int row = c * 64 + srow;                                              \
            gload_lds16(Abase + (size_t)(p0 + row) * 1024 + (kt) * 64 + gcol,     \
                        &As[buf][row * 64 + schunk * 8]);                         \
        }                                                                         \
        _Pragma("unroll")                                                         \
        for (int c = 0; c < 4; c++) {                                             \
            int row = c * 64 + srow;                                              \
            gload_lds16(xt + (size_t)tok[c] * 1024 + (kt) * 64 + gcol,            \
                        &Bs[buf][row * 64 + schunk * 8]);                         \
        }                                                                         \
    } while (0)

    const int rsw = r16 & 7;

    STAGE(0, 0);                                 // 8 outstanding
    STAGE(1, 1);                                 // 16 outstanding
    asm volatile("s_waitcnt vmcnt(8)" ::: "memory");   // buf0 landed
    __builtin_amdgcn_sched_barrier(0);
    __builtin_amdgcn_s_barrier();

    #pragma unroll 2
    for (int kt = 0; kt < 16; kt++) {
        const int cur = kt & 1;
        // ---- compute buf[cur] ----
        #pragma unroll
        for (int kk = 0; kk < 2; kk++) {
            const int ch = ((kk * 4 + q) ^ rsw) * 8;
            bf16x8 af[8], bfr[4];
            #pragma unroll
            for (int m = 0; m < 8; m++)
                af[m] = *reinterpret_cast<const bf16x8*>(
                    &As[cur][(wr * 128 + m * 16 + r16) * 64 + ch]);
            #pragma unroll
            for (int nn = 0; nn < 4; nn++)
                bfr[nn] = *reinterpret_cast<const bf16x8*>(
                    &Bs[cur][(wc * 64 + nn * 16 + r16) * 64 + ch]);
            #pragma unroll
            for (int m = 0; m < 8; m++)
                #pragma unroll
                for (int nn = 0; nn < 4; nn++)
                    acc[m][nn] = __builtin_amdgcn_mfma_f32_16x16x32_bf16(
                        af[m], bfr[nn], acc[m][nn], 0, 0, 0);
        }
        // ---- all waves done reading buf[cur] ----
        __builtin_amdgcn_sched_barrier(0);
        __builtin_amdgcn_s_barrier();
        if (kt < 14) {
            STAGE(cur, kt + 2);                  // 16 outstanding
            asm volatile("s_waitcnt vmcnt(8)" ::: "memory");  // buf[cur^1] landed
        } else {
            asm volatile("s_waitcnt vmcnt(0)" ::: "memory");  // final drain
        }
        __builtin_amdgcn_sched_barrier(0);
        __builtin_amdgcn_s_barrier();
    }
    #undef STAGE

    float bv[8][4];
    #pragma unroll
    for (int m = 0; m < 8; m++)
        #pragma unroll
        for (int r = 0; r < 4; r++)
            bv[m][r] = expert_b[e * 1024 + p0 + wr * 128 + m * 16 + q * 4 + r];

    #pragma unroll
    for (int nn = 0; nn < 4; nn++) {
        const int j = wc * 64 + nn * 16 + r16;
        if (j < cnt_local) {
            const size_t rowb = (size_t)(pbase + j) * 1024;
            #pragma unroll
            for (int m = 0; m < 8; m++) {
                ushort4 o;
                o.x = f2bf(acc[m][nn][0] + bv[m][0]);
                o.y = f2bf(acc[m][nn][1] + bv[m][1]);
                o.z = f2bf(acc[m][nn][2] + bv[m][2]);
                o.w = f2bf(acc[m][nn][3] + bv[m][3]);
                *reinterpret_cast<ushort4*>(&tmp[rowb + p0 + wr * 128 + m * 16 + q * 4]) = o;
            }
        }
    }
}

// ---------------------------------------------------------------------------
// Combine: out[b,p,n] = w0[t]*tmp[posA[t]][p] + w1[t]*tmp[posB[t]][p]
// ---------------------------------------------------------------------------
__global__ __launch_bounds__(256) void combine_kernel(
    const unsigned short* __restrict__ tmp,
    const int* __restrict__ posA, const int* __restrict__ posB,
    const float* __restrict__ w0a, const float* __restrict__ w1a,
    float* __restrict__ out)
{
    __shared__ unsigned short l0[64 * 128];
    __shared__ unsigned short l1[64 * 128];
    __shared__ float sw0[64], sw1[64];
    const int tid = threadIdx.x;
    const int b = blockIdx.z;
    const int p0 = blockIdx.y * 128;
    const int n0 = blockIdx.x * 64;

    if (tid < 64) {
        int t = b * 512 + n0 + tid;
        sw0[tid] = w0a[t];
        sw1[tid] = w1a[t];
    }

    #pragma unroll
    for (int pass = 0; pass < 8; pass++) {
        int rowid = pass * 16 + (tid >> 4);
        int slot = rowid >> 6, j = rowid & 63;
        int t = b * 512 + n0 + j;
        int pos = slot ? posB[t] : posA[t];
        u16x8 v = *reinterpret_cast<const u16x8*>(&tmp[(size_t)pos * 1024 + p0 + (tid & 15) * 8]);
        unsigned short* dst = slot ? l1 : l0;
        int c0 = (tid & 15) * 8;
        int sw = (j & 31) << 2;
        ushort4 a; a.x = v[0]; a.y = v[1]; a.z = v[2]; a.w = v[3];
        ushort4 bq; bq.x = v[4]; bq.y = v[5]; bq.z = v[6]; bq.w = v[7];
        *reinterpret_cast<ushort4*>(&dst[j * 128 + (c0 ^ sw)]) = a;
        *reinterpret_cast<ushort4*>(&dst[j * 128 + ((c0 + 4) ^ sw)]) = bq;
    }
    __syncthreads();

    const int j = tid & 63;
    const int wv = tid >> 6;
    const float wa = sw0[j], wb = sw1[j];
    const int sw = (j & 31) << 2;
    #pragma unroll 8
    for (int pp = 0; pp < 32; pp++) {
        int p = wv * 32 + pp;
        float v0 = bf2f(l0[j * 128 + (p ^ sw)]);
        float v1 = bf2f(l1[j * 128 + (p ^ sw)]);
        out[((size_t)b * 1024 + p0 + p) * 512 + n0 + j] = wa * v0 + wb * v1;
    }
}

// ---------------------------------------------------------------------------
// Fallback dense kernel (only if ws too small — not expected).
// ---------------------------------------------------------------------------
__global__ __launch_bounds__(256, 2) void moe_dense_idx_kernel(
    const unsigned short* __restrict__ Wt,
    const unsigned short* __restrict__ xt,
    const int* __restrict__ e01,
    const float* __restrict__ w0a, const float* __restrict__ w1a,
    const float* __restrict__ expert_b,
    float* __restrict__ out)
{
    __shared__ unsigned short As[128 * 64];
    __shared__ unsigned short Bs[128 * 64];

    const int tid  = threadIdx.x;
    const int wave = tid >> 6, lane = tid & 63;
    const int wr = wave >> 1, wc = wave & 1;
    const int q = lane >> 4, r16 = lane & 15;
    const int b  = blockIdx.z;
    const int p0 = blockIdx.y * 128;
    const int n0 = blockIdx.x * 128;

    const unsigned short* Bbase = xt + (size_t)b * 512 * 1024;
    const int srow = tid >> 3;
    const int scol = (tid & 7) * 8;

    f32x4 out_acc[4][4];
    #pragma unroll
    for (int m = 0; m < 4; m++)
        #pragma unroll
        for (int nn = 0; nn < 4; nn++)
            out_acc[m][nn] = (f32x4){0.f, 0.f, 0.f, 0.f};

    for (int e = 0; e < 8; e++) {
        const unsigned short* Abase = Wt + (size_t)e * 1024 * 1024;
        f32x4 acc[4][4];
        #pragma unroll
        for (int m = 0; m < 4; m++)
            #pragma unroll
            for (int nn = 0; nn < 4; nn++)
                acc[m][nn] = (f32x4){0.f, 0.f, 0.f, 0.f};

        for (int kt = 0; kt < 16; kt++) {
            __syncthreads();
            #pragma unroll
            for (int c = 0; c < 4; c++) {
                int row = c * 32 + srow;
                gload_lds16(Abase + (size_t)(p0 + row) * 1024 + kt * 64 + scol,
                            &As[row * 64 + scol]);
            }
            #pragma unroll
            for (int c = 0; c < 4; c++) {
                int row = c * 32 + srow;
                gload_lds16(Bbase + (size_t)(n0 + row) * 1024 + kt * 64 + scol,
                            &Bs[row * 64 + scol]);
            }
            __syncthreads();
            #pragma unroll
            for (int kk = 0; kk < 2; kk++) {
                bf16x8 af[4], bfr[4];
                #pragma unroll
                for (int m = 0; m < 4; m++) {
                    af[m]  = *reinterpret_cast<const bf16x8*>(&As[(wr * 64 + m * 16 + r16) * 64 + kk * 32 + q * 8]);
                    bfr[m] = *reinterpret_cast<const bf16x8*>(&Bs[(wc * 64 + m * 16 + r16) * 64 + kk * 32 + q * 8]);
                }
                #pragma unroll
                for (int m = 0; m < 4; m++)
                    #pragma unroll
                    for (int nn = 0; nn < 4; nn++)
                        acc[m][nn] = __builtin_amdgcn_mfma_f32_16x16x32_bf16(
                            af[m], bfr[nn], acc[m][nn], 0, 0, 0);
            }
        }
        float cw[4], bv[4][4];
        #pragma unroll
        for (int nn = 0; nn < 4; nn++) {
            int t = b * 512 + n0 + wc * 64 + nn * 16 + r16;
            int ev = e01[t];
            cw[nn] = (e == (ev & 255)) ? w0a[t] : ((e == (ev >> 8)) ? w1a[t] : 0.f);
        }
        #pragma unroll
        for (int m = 0; m < 4; m++)
            #pragma unroll
            for (int r = 0; r < 4; r++)
                bv[m][r] = expert_b[e * 1024 + p0 + wr * 64 + m * 16 + q * 4 + r];
        #pragma unroll
        for (int m = 0; m < 4; m++)
            #pragma unroll
            for (int nn = 0; nn < 4; nn++)
                #pragma unroll
                for (int r = 0; r < 4; r++)
                    out_acc[m][nn][r] += cw[nn] * (acc[m][nn][r] + bv[m][r]);
    }
    #pragma unroll
    for (int m = 0; m < 4; m++)
        #pragma unroll
        for (int nn = 0; nn < 4; nn++)
            #pragma unroll
            for (int r = 0; r < 4; r++) {
                int p = p0 + wr * 64 + m * 16 + q * 4 + r;
                int n = n0 + wc * 64 + nn * 16 + r16;
                out[(size_t)b * 1024 * 512 + (size_t)p * 512 + n] = out_acc[m][nn][r];
            }
}

// ---------------------------------------------------------------------------
extern "C" void kernel_launch(void* const* d_in, const int* in_sizes, int n_in,
                              void* d_out, int out_size, void* d_ws, size_t ws_size,
                              hipStream_t stream) {
    const float* x        = (const float*)d_in[0];   // [64][1024][512]
    const float* gate_W   = (const float*)d_in[1];   // [1024][8]
    const float* expert_W = (const float*)d_in[2];   // [8][1024][1024]
    const float* expert_b = (const float*)d_in[3];   // [8][1024]
    float* out = (float*)d_out;                      // [64][1024][512] + [512][8]

    char* ws = (char*)d_ws;
    unsigned short* Wt  = (unsigned short*)(ws + 0);          // 16 MB
    unsigned short* xt  = (unsigned short*)(ws + 16777216);   // 64 MB
    float* gate  = (float*)(ws + 83886080);                   // 1 MB
    float* w0a   = (float*)(ws + 84934656);                   // 128 KB
    float* w1a   = (float*)(ws + 85065728);                   // 128 KB
    int*   e01   = (int*)(ws + 85196800);                     // 128 KB
    int*   hist  = (int*)(ws + 85327872);                     // 8 KB
    int*   coff  = (int*)(ws + 85336064);                     // 8 KB
    int*   meta  = (int*)(ws + 85344256);                     // 256 B
    int*   perm  = (int*)(ws + 85344512);                     // 256 KB
    int*   posA  = (int*)(ws + 85606656);                     // 128 KB
    int*   posB  = (int*)(ws + 85737728);                     // 128 KB
    unsigned short* tmp = (unsigned short*)(ws + 85868800);   // 134.2 MB
    // plog (16 MB) aliases tmp's head: consumed by gate_stage2 before
    // grouped_gemm writes tmp (stream-ordered).
    float* plog = (float*)(ws + 85868800);
    const size_t NEEDED = 85868800ull + 134217728ull;         // ~210 MB

    transpose_cast_kernel<<<dim3(16, 16, 8), 256, 0, stream>>>(expert_W, Wt, 1024, 1024);
    transpose_x_gate_kernel<<<dim3(8, 16, 64), 256, 0, stream>>>(x, gate_W, xt, plog);

    gate_stage2_kernel<<<128, 256, 0, stream>>>(plog, gate, e01, w0a, w1a, hist);
    gate_mean_kernel<<<16, 256, 0, stream>>>(gate, out + 33554432);

    if (ws_size >= NEEDED) {
        scan_kernel<<<1, 256, 0, stream>>>(hist, coff, meta);
        fill_kernel<<<128, 256, 0, stream>>>(e01, coff, perm, posA, posB);
        grouped_gemm_kernel<<<dim3(1088), 512, 0, stream>>>(Wt, xt, perm, meta, expert_b, tmp);
        combine_kernel<<<dim3(8, 8, 64), 256, 0, stream>>>(tmp, posA, posB, w0a, w1a, out);
    } else {
        moe_dense_idx_kernel<<<dim3(4, 8, 64), 256, 0, stream>>>(Wt, xt, e01, w0a, w1a, expert_b, out);
    }
}

// Round 7
// 306.541 us; speedup vs baseline: 1.0294x; 1.0294x over previous
//
#include <hip/hip_runtime.h>
#include <cstddef>

typedef __bf16 bf16x8 __attribute__((ext_vector_type(8)));
typedef float  f32x4  __attribute__((ext_vector_type(4)));
typedef unsigned short u16x8 __attribute__((ext_vector_type(8)));

#define GLOBAL_AS __attribute__((address_space(1)))
#define LDS_AS    __attribute__((address_space(3)))

__device__ __forceinline__ void gload_lds16(const void* g, void* l) {
    __builtin_amdgcn_global_load_lds((const GLOBAL_AS unsigned int*)g,
                                     (LDS_AS unsigned int*)l, 16, 0, 0);
}

__device__ __forceinline__ unsigned short f2bf(float f) {
    union { float f; unsigned int u; } v; v.f = f;
    unsigned int r = v.u + 0x7FFFu + ((v.u >> 16) & 1u);   // RNE
    return (unsigned short)(r >> 16);
}
__device__ __forceinline__ float bf2f(unsigned short h) {
    union { unsigned int u; float f; } v; v.u = ((unsigned int)h) << 16;
    return v.f;
}

// ---------------------------------------------------------------------------
// Transpose + cast (expert_W): src [batch][R][C] f32 -> dst [batch][C][R] bf16
// ---------------------------------------------------------------------------
__global__ __launch_bounds__(256) void transpose_cast_kernel(
    const float* __restrict__ src, unsigned short* __restrict__ dst,
    int R, int C)
{
    const int bat = blockIdx.z;
    src += (size_t)bat * R * C;
    dst += (size_t)bat * R * C;
    const int r0 = blockIdx.y * 64, c0 = blockIdx.x * 64;
    __shared__ float t[64][65];
    const int tid = threadIdx.x;
    const int rr = tid >> 4;
    const int cc = (tid & 15) * 4;

    #pragma unroll
    for (int p = 0; p < 4; p++) {
        int r = p * 16 + rr;
        const float4 v = *reinterpret_cast<const float4*>(&src[(size_t)(r0 + r) * C + c0 + cc]);
        t[r][cc + 0] = v.x; t[r][cc + 1] = v.y; t[r][cc + 2] = v.z; t[r][cc + 3] = v.w;
    }
    __syncthreads();
    #pragma unroll
    for (int p = 0; p < 4; p++) {
        int c = p * 16 + rr;
        ushort4 o;
        o.x = f2bf(t[cc + 0][c]); o.y = f2bf(t[cc + 1][c]);
        o.z = f2bf(t[cc + 2][c]); o.w = f2bf(t[cc + 3][c]);
        *reinterpret_cast<ushort4*>(&dst[(size_t)(c0 + c) * R + r0 + cc]) = o;
    }
}

// ---------------------------------------------------------------------------
// x transpose + fused gate partial-logits.
// ---------------------------------------------------------------------------
__global__ __launch_bounds__(256) void transpose_x_gate_kernel(
    const float* __restrict__ src, const float* __restrict__ gW,
    unsigned short* __restrict__ dst, float* __restrict__ plog)
{
    const int bat = blockIdx.z;
    const int R = 1024, C = 512;
    const float* srcb = src + (size_t)bat * R * C;
    unsigned short* dstb = dst + (size_t)bat * R * C;
    const int r0 = blockIdx.y * 64, c0 = blockIdx.x * 64;
    __shared__ float t[64][65];
    __shared__ float gWs[64][8];
    __shared__ float pacc[4][64][9];
    const int tid = threadIdx.x;
    const int rr = tid >> 4;
    const int cc = (tid & 15) * 4;

    if (tid < 128) {
        reinterpret_cast<float4*>(&gWs[0][0])[tid] =
            reinterpret_cast<const float4*>(gW + (size_t)r0 * 8)[tid];
    }
    #pragma unroll
    for (int p = 0; p < 4; p++) {
        int r = p * 16 + rr;
        const float4 v = *reinterpret_cast<const float4*>(&srcb[(size_t)(r0 + r) * C + c0 + cc]);
        t[r][cc + 0] = v.x; t[r][cc + 1] = v.y; t[r][cc + 2] = v.z; t[r][cc + 3] = v.w;
    }
    __syncthreads();
    #pragma unroll
    for (int p = 0; p < 4; p++) {
        int c = p * 16 + rr;
        ushort4 o;
        o.x = f2bf(t[cc + 0][c]); o.y = f2bf(t[cc + 1][c]);
        o.z = f2bf(t[cc + 2][c]); o.w = f2bf(t[cc + 3][c]);
        *reinterpret_cast<ushort4*>(&dstb[(size_t)(c0 + c) * R + r0 + cc]) = o;
    }

    {
        const int nl = tid & 63;
        const int sc = tid >> 6;
        float a[8];
        #pragma unroll
        for (int e = 0; e < 8; e++) a[e] = 0.f;
        for (int s = sc * 16; s < sc * 16 + 16; s++) {
            float xv = t[s][nl];
            #pragma unroll
            for (int e = 0; e < 8; e++) a[e] = fmaf(xv, gWs[s][e], a[e]);
        }
        #pragma unroll
        for (int e = 0; e < 8; e++) pacc[sc][nl][e] = a[e];
        __syncthreads();
        if (tid < 64) {
            const size_t base = (((size_t)bat * 16 + blockIdx.y) * 512 + c0 + tid) * 8;
            #pragma unroll
            for (int e = 0; e < 8; e++) {
                float v = ((pacc[0][tid][e] + pacc[1][tid][e]) + pacc[2][tid][e]) + pacc[3][tid][e];
                plog[base + e] = v;
            }
        }
    }
}

// ---------------------------------------------------------------------------
// Gate stage 2: reduce partials (fixed order), softmax, top-2, histogram.
// ---------------------------------------------------------------------------
__global__ __launch_bounds__(256) void gate_stage2_kernel(
    const float* __restrict__ plog,
    float* __restrict__ gate, int* __restrict__ e01,
    float* __restrict__ w0a, float* __restrict__ w1a,
    int* __restrict__ hist)
{
    __shared__ int h[16];
    const int tid = threadIdx.x;
    if (tid < 16) h[tid] = 0;
    __syncthreads();

    const int t = blockIdx.x * 256 + tid;
    const int b = t >> 9;
    const int n = t & 511;

    float acc[8];
    #pragma unroll
    for (int e = 0; e < 8; e++) acc[e] = 0.f;
    for (int y = 0; y < 16; y++) {
        const float* pp = plog + (((size_t)b * 16 + y) * 512 + n) * 8;
        const float4 lo = *reinterpret_cast<const float4*>(pp);
        const float4 hi = *reinterpret_cast<const float4*>(pp + 4);
        acc[0] += lo.x; acc[1] += lo.y; acc[2] += lo.z; acc[3] += lo.w;
        acc[4] += hi.x; acc[5] += hi.y; acc[6] += hi.z; acc[7] += hi.w;
    }
    float m = acc[0];
    #pragma unroll
    for (int e = 1; e < 8; e++) m = fmaxf(m, acc[e]);
    float p[8], s = 0.f;
    #pragma unroll
    for (int e = 0; e < 8; e++) { p[e] = __expf(acc[e] - m); s += p[e]; }
    float inv = 1.f / s;
    #pragma unroll
    for (int e = 0; e < 8; e++) p[e] *= inv;

    int e0 = 0;
    #pragma unroll
    for (int e = 1; e < 8; e++) if (p[e] > p[e0]) e0 = e;
    int e1 = -1;
    #pragma unroll
    for (int e = 0; e < 8; e++) {
        if (e == e0) continue;
        if (e1 < 0 || p[e] > p[e1]) e1 = e;
    }

    const size_t base = (size_t)t * 8;
    #pragma unroll
    for (int e = 0; e < 8; e++) gate[base + e] = p[e];
    e01[t] = e0 | (e1 << 8);
    w0a[t] = p[e0];
    w1a[t] = p[e1];

    atomicAdd(&h[e0], 1);
    atomicAdd(&h[8 + e1], 1);
    __syncthreads();
    if (tid < 16) hist[blockIdx.x * 16 + tid] = h[tid];
}

__global__ __launch_bounds__(256) void gate_mean_kernel(
    const float* __restrict__ gate, float* __restrict__ out)
{
    const int idx = blockIdx.x * 256 + threadIdx.x;
    float s = 0.f;
    #pragma unroll 8
    for (int b = 0; b < 64; b++) s += gate[(size_t)b * 4096 + idx];
    out[idx] = s * (1.f / 64.f);
}

// ---------------------------------------------------------------------------
// Scan: hist[128][16] -> chunk_off, meta { base[16], cnt[16], tile_scan[17] }
// tile granularity = 256 tokens.
// ---------------------------------------------------------------------------
__global__ __launch_bounds__(256) void scan_kernel(
    const int* __restrict__ hist, int* __restrict__ chunk_off,
    int* __restrict__ meta)
{
    __shared__ int cnt_s[16];
    const int tid = threadIdx.x;
    if (tid < 16) {
        int run = 0;
        for (int c = 0; c < 128; c++) {
            chunk_off[c * 16 + tid] = run;
            run += hist[c * 16 + tid];
        }
        cnt_s[tid] = run;
        meta[16 + tid] = run;
    }
    __syncthreads();
    __shared__ int base_s[16];
    if (tid == 0) {
        int run = 0, trun = 0;
        meta[32] = 0;
        for (int g = 0; g < 16; g++) {
            base_s[g] = run;
            meta[g] = run;
            run += cnt_s[g];
            trun += (cnt_s[g] + 255) >> 8;      // 256-token tiles
            meta[33 + g] = trun;
        }
    }
    __syncthreads();
    for (int i = tid; i < 2048; i += 256)
        chunk_off[i] += base_s[i & 15];
}

// ---------------------------------------------------------------------------
// Fill: stable counting-sort placement, ballot-based ranking.
// ---------------------------------------------------------------------------
__global__ __launch_bounds__(256) void fill_kernel(
    const int* __restrict__ e01, const int* __restrict__ chunk_off,
    int* __restrict__ perm, int* __restrict__ posA, int* __restrict__ posB)
{
    __shared__ int wh[4][16];
    const int tid = threadIdx.x;
    const int wv = tid >> 6, lane = tid & 63;
    const int chunk = blockIdx.x;
    const int t = chunk * 256 + tid;
    const int ev = e01[t];
    const int e0 = ev & 255, e1 = ev >> 8;

    const unsigned long long ltmask = (lane == 63) ? 0x7FFFFFFFFFFFFFFFull
                                                   : ((1ull << lane) - 1ull);
    unsigned long long m0sel = 0, m1sel = 0;
    #pragma unroll
    for (int e = 0; e < 8; e++) {
        unsigned long long b0 = __ballot(e0 == e);
        unsigned long long b1 = __ballot(e1 == e);
        if (e0 == e) m0sel = b0;
        if (e1 == e) m1sel = b1;
        if (lane == 0) {
            wh[wv][e]     = __popcll(b0);
            wh[wv][8 + e] = __popcll(b1);
        }
    }
    const int r0l = __popcll(m0sel & ltmask);
    const int r1l = __popcll(m1sel & ltmask);
    __syncthreads();

    int off0 = 0, off1 = 0;
    for (int w = 0; w < wv; w++) { off0 += wh[w][e0]; off1 += wh[w][8 + e1]; }

    const int p0 = chunk_off[chunk * 16 + e0] + off0 + r0l;
    const int p1 = chunk_off[chunk * 16 + 8 + e1] + off1 + r1l;
    perm[p0] = t; perm[p1] = t;
    posA[t] = p0; posB[t] = p1;
}

// ---------------------------------------------------------------------------
// Grouped GEMM: 256x256x64, 512 threads (8 waves = 2p x 4tok), 8-phase
// schedule (m201 template): 4 phases per K-tile, each {ds_read quadrant frags
// | stage one half-tile -> s_barrier -> setprio MFMA -> s_barrier}, counted
// vmcnt(4) once per K-tile. A staged 1 tile ahead (L2-warm W), B staged 2
// tiles ahead (HBM-cold xt). T2 chunk-XOR swizzle (0 conflicts, r5-verified).
// XCD-aware 1D grid. Raw barriers (no compiler vmcnt-drain).
// ---------------------------------------------------------------------------
__global__ __launch_bounds__(512, 2) void grouped_gemm_kernel(
    const unsigned short* __restrict__ Wt,      // [8][1024 p][1024 s]
    const unsigned short* __restrict__ xt,      // [32768 tok][1024 s]
    const int* __restrict__ perm,
    const int* __restrict__ meta,               // base[16],cnt[16],tile_scan[17]
    const float* __restrict__ expert_b,
    unsigned short* __restrict__ tmp)           // [65536][1024]
{
    const int d    = blockIdx.x;                // 0..1087
    const int xcd  = d & 7;
    const int jj   = d >> 3;                    // 0..135
    const int tile = xcd * 34 + (jj >> 2);      // 0..271
    const int p0   = (jj & 3) * 256;

    int g = -1;
    #pragma unroll
    for (int gg = 0; gg < 16; gg++) {
        if (tile >= meta[32 + gg] && tile < meta[33 + gg]) g = gg;
    }
    if (g < 0) return;
    const int lt = tile - meta[32 + g];
    const int e = g & 7;
    const int cnt_local = meta[16 + g] - lt * 256;
    const int pbase = meta[g] + lt * 256;

    __shared__ unsigned short As[2][256 * 64];  // 64 KB
    __shared__ unsigned short Bs[2][256 * 64];  // 64 KB

    const int tid  = threadIdx.x;
    const int wid  = tid >> 6, lane = tid & 63;
    const int wr = wid >> 2, wc = wid & 3;      // 2 (p) x 4 (tok)
    const int q = lane >> 4, r16 = lane & 15;
    const int rsw = r16 & 7;

    const int srow8  = tid >> 3;                // 0..63
    const int schunk = tid & 7;
    const int gcol   = (schunk ^ (srow8 & 7)) * 8;

    const unsigned short* Abase = Wt + (size_t)e * 1024 * 1024;

    int tok[4];
    #pragma unroll
    for (int c = 0; c < 4; c++) {
        int row = c * 64 + srow8;
        int idx = row < cnt_local ? row : 0;
        tok[c] = perm[pbase + idx];
    }

    f32x4 acc[8][4];
    #pragma unroll
    for (int m = 0; m < 8; m++)
        #pragma unroll
        for (int nn = 0; nn < 4; nn++)
            acc[m][nn] = (f32x4){0.f, 0.f, 0.f, 0.f};

    bf16x8 afr[8];          // current mh: [m*2+kk]
    bf16x8 bfr[2][4];       // [nh][nn*2+kk]

    // ---- stage macros: one 128-row half-tile (2 gload_lds per thread) ----
    #define STAGE_A(buf, kt, half) do {                                          \
        _Pragma("unroll")                                                        \
        for (int r = 0; r < 2; r++) {                                            \
            int row = (half) * 128 + r * 64 + srow8;                             \
            gload_lds16(Abase + (size_t)(p0 + row) * 1024 + (kt) * 64 + gcol,    \
                        &As[buf][row * 64 + schunk * 8]);                        \
        } } while (0)
    #define STAGE_B(buf, kt, half) do {                                          \
        _Pragma("unroll")                                                        \
        for (int r = 0; r < 2; r++) {                                            \
            int row = (half) * 128 + r * 64 + srow8;                             \
            gload_lds16(xt + (size_t)tok[(half) * 2 + r] * 1024 + (kt) * 64 + gcol, \
                        &Bs[buf][row * 64 + schunk * 8]);                        \
        } } while (0)

    // ---- ds_read macros (quadrant operands, swizzled) ----
    #define DS_A(MH) do {                                                        \
        _Pragma("unroll")                                                        \
        for (int m = 0; m < 4; m++)                                              \
            _Pragma("unroll")                                                    \
            for (int kk = 0; kk < 2; kk++)                                       \
                afr[m * 2 + kk] = *reinterpret_cast<const bf16x8*>(              \
                    &As[cur][(wr * 128 + (MH) * 64 + m * 16 + r16) * 64          \
                             + (((kk * 4 + q) ^ rsw) * 8)]);                     \
        } while (0)
    #define DS_B(NH) do {                                                        \
        _Pragma("unroll")                                                        \
        for (int nn = 0; nn < 2; nn++)                                           \
            _Pragma("unroll")                                                    \
            for (int kk = 0; kk < 2; kk++)                                       \
                bfr[NH][nn * 2 + kk] = *reinterpret_cast<const bf16x8*>(         \
                    &Bs[cur][(wc * 64 + (NH) * 32 + nn * 16 + r16) * 64          \
                             + (((kk * 4 + q) ^ rsw) * 8)]);                     \
        } while (0)

    #define MFMA_Q(MH, NH) do {                                                  \
        __builtin_amdgcn_s_setprio(1);                                           \
        _Pragma("unroll")                                                        \
        for (int kk = 0; kk < 2; kk++)                                           \
            _Pragma("unroll")                                                    \
            for (int m = 0; m < 4; m++)                                          \
                _Pragma("unroll")                                                \
                for (int nn = 0; nn < 2; nn++)                                   \
                    acc[(MH) * 4 + m][(NH) * 2 + nn] =                           \
                        __builtin_amdgcn_mfma_f32_16x16x32_bf16(                 \
                            afr[m * 2 + kk], bfr[NH][nn * 2 + kk],               \
                            acc[(MH) * 4 + m][(NH) * 2 + nn], 0, 0, 0);          \
        __builtin_amdgcn_s_setprio(0);                                           \
        } while (0)

    #define SBAR do {                                                            \
        __builtin_amdgcn_sched_barrier(0);                                       \
        __builtin_amdgcn_s_barrier();                                            \
        __builtin_amdgcn_sched_barrier(0);                                       \
        } while (0)

    // ---- prologue: tile0 fully + B halves of tile1; wait tile0 ----
    STAGE_A(0, 0, 0); STAGE_A(0, 0, 1);
    STAGE_B(0, 0, 0); STAGE_B(0, 0, 1);
    STAGE_B(1, 1, 0); STAGE_B(1, 1, 1);
    asm volatile("s_waitcnt vmcnt(4)" ::: "memory");
    SBAR;

    #pragma unroll 2
    for (int kt = 0; kt < 16; kt++) {
        const int cur = kt & 1;
        const int nxt = cur ^ 1;

        // phase 1: Q(0,0); stage A-top(kt+1)
        DS_A(0); DS_B(0);
        if (kt < 15) STAGE_A(nxt, kt + 1, 0);
        asm volatile("s_waitcnt lgkmcnt(8)" ::: "memory");
        SBAR;
        MFMA_Q(0, 0);
        SBAR;

        // phase 2: Q(0,1); stage A-bot(kt+1)
        DS_B(1);
        if (kt < 15) STAGE_A(nxt, kt + 1, 1);
        SBAR;
        MFMA_Q(0, 1);
        SBAR;

        // phase 3: Q(1,0); stage B-top(kt+2)  [B-top(kt) freed after p2]
        DS_A(1);
        if (kt < 14) STAGE_B(cur, kt + 2, 0);
        SBAR;
        MFMA_Q(1, 0);
        SBAR;

        // phase 4: Q(1,1); stage B-bot(kt+2); counted vmcnt (once per K-tile)
        if (kt < 14) STAGE_B(cur, kt + 2, 1);
        SBAR;
        MFMA_Q(1, 1);
        if (kt <= 13) {
            asm volatile("s_waitcnt vmcnt(4)" ::: "memory");
        } else if (kt == 14) {
            asm volatile("s_waitcnt vmcnt(0)" ::: "memory");
        }
        SBAR;
    }

    #undef STAGE_A
    #undef STAGE_B
    #undef DS_A
    #undef DS_B
    #undef MFMA_Q
    #undef SBAR

    float bv[8][4];
    #pragma unroll
    for (int m = 0; m < 8; m++)
        #pragma unroll
        for (int r = 0; r < 4; r++)
            bv[m][r] = expert_b[e * 1024 + p0 + wr * 128 + m * 16 + q * 4 + r];

    #pragma unroll
    for (int nn = 0; nn < 4; nn++) {
        const int j = wc * 64 + nn * 16 + r16;
        if (j < cnt_local) {
            const size_t rowb = (size_t)(pbase + j) * 1024;
            #pragma unroll
            for (int m = 0; m < 8; m++) {
                ushort4 o;
                o.x = f2bf(acc[m][nn][0] + bv[m][0]);
                o.y = f2bf(acc[m][nn][1] + bv[m][1]);
                o.z = f2bf(acc[m][nn][2] + bv[m][2]);
                o.w = f2bf(acc[m][nn][3] + bv[m][3]);
                *reinterpret_cast<ushort4*>(&tmp[rowb + p0 + wr * 128 + m * 16 + q * 4]) = o;
            }
        }
    }
}

// ---------------------------------------------------------------------------
// Combine: out[b,p,n] = w0[t]*tmp[posA[t]][p] + w1[t]*tmp[posB[t]][p]
// ---------------------------------------------------------------------------
__global__ __launch_bounds__(256) void combine_kernel(
    const unsigned short* __restrict__ tmp,
    const int* __restrict__ posA, const int* __restrict__ posB,
    const float* __restrict__ w0a, const float* __restrict__ w1a,
    float* __restrict__ out)
{
    __shared__ unsigned short l0[64 * 128];
    __shared__ unsigned short l1[64 * 128];
    __shared__ float sw0[64], sw1[64];
    const int tid = threadIdx.x;
    const int b = blockIdx.z;
    const int p0 = blockIdx.y * 128;
    const int n0 = blockIdx.x * 64;

    if (tid < 64) {
        int t = b * 512 + n0 + tid;
        sw0[tid] = w0a[t];
        sw1[tid] = w1a[t];
    }

    #pragma unroll
    for (int pass = 0; pass < 8; pass++) {
        int rowid = pass * 16 + (tid >> 4);
        int slot = rowid >> 6, j = rowid & 63;
        int t = b * 512 + n0 + j;
        int pos = slot ? posB[t] : posA[t];
        u16x8 v = *reinterpret_cast<const u16x8*>(&tmp[(size_t)pos * 1024 + p0 + (tid & 15) * 8]);
        unsigned short* dst = slot ? l1 : l0;
        int c0 = (tid & 15) * 8;
        int sw = (j & 31) << 2;
        ushort4 a; a.x = v[0]; a.y = v[1]; a.z = v[2]; a.w = v[3];
        ushort4 bq; bq.x = v[4]; bq.y = v[5]; bq.z = v[6]; bq.w = v[7];
        *reinterpret_cast<ushort4*>(&dst[j * 128 + (c0 ^ sw)]) = a;
        *reinterpret_cast<ushort4*>(&dst[j * 128 + ((c0 + 4) ^ sw)]) = bq;
    }
    __syncthreads();

    const int j = tid & 63;
    const int wv = tid >> 6;
    const float wa = sw0[j], wb = sw1[j];
    const int sw = (j & 31) << 2;
    #pragma unroll 8
    for (int pp = 0; pp < 32; pp++) {
        int p = wv * 32 + pp;
        float v0 = bf2f(l0[j * 128 + (p ^ sw)]);
        float v1 = bf2f(l1[j * 128 + (p ^ sw)]);
        out[((size_t)b * 1024 + p0 + p) * 512 + n0 + j] = wa * v0 + wb * v1;
    }
}

// ---------------------------------------------------------------------------
// Fallback dense kernel (only if ws too small — not expected).
// ---------------------------------------------------------------------------
__global__ __launch_bounds__(256, 2) void moe_dense_idx_kernel(
    const unsigned short* __restrict__ Wt,
    const unsigned short* __restrict__ xt,
    const int* __restrict__ e01,
    const float* __restrict__ w0a, const float* __restrict__ w1a,
    const float* __restrict__ expert_b,
    float* __restrict__ out)
{
    __shared__ unsigned short As[128 * 64];
    __shared__ unsigned short Bs[128 * 64];

    const int tid  = threadIdx.x;
    const int wave = tid >> 6, lane = tid & 63;
    const int wr = wave >> 1, wc = wave & 1;
    const int q = lane >> 4, r16 = lane & 15;
    const int b  = blockIdx.z;
    const int p0 = blockIdx.y * 128;
    const int n0 = blockIdx.x * 128;

    const unsigned short* Bbase = xt + (size_t)b * 512 * 1024;
    const int srow = tid >> 3;
    const int scol = (tid & 7) * 8;

    f32x4 out_acc[4][4];
    #pragma unroll
    for (int m = 0; m < 4; m++)
        #pragma unroll
        for (int nn = 0; nn < 4; nn++)
            out_acc[m][nn] = (f32x4){0.f, 0.f, 0.f, 0.f};

    for (int e = 0; e < 8; e++) {
        const unsigned short* Abase = Wt + (size_t)e * 1024 * 1024;
        f32x4 acc[4][4];
        #pragma unroll
        for (int m = 0; m < 4; m++)
            #pragma unroll
            for (int nn = 0; nn < 4; nn++)
                acc[m][nn] = (f32x4){0.f, 0.f, 0.f, 0.f};

        for (int kt = 0; kt < 16; kt++) {
            __syncthreads();
            #pragma unroll
            for (int c = 0; c < 4; c++) {
                int row = c * 32 + srow;
                gload_lds16(Abase + (size_t)(p0 + row) * 1024 + kt * 64 + scol,
                            &As[row * 64 + scol]);
            }
            #pragma unroll
            for (int c = 0; c < 4; c++) {
                int row = c * 32 + srow;
                gload_lds16(Bbase + (size_t)(n0 + row) * 1024 + kt * 64 + scol,
                            &Bs[row * 64 + scol]);
            }
            __syncthreads();
            #pragma unroll
            for (int kk = 0; kk < 2; kk++) {
                bf16x8 af[4], bfr[4];
                #pragma unroll
                for (int m = 0; m < 4; m++) {
                    af[m]  = *reinterpret_cast<const bf16x8*>(&As[(wr * 64 + m * 16 + r16) * 64 + kk * 32 + q * 8]);
                    bfr[m] = *reinterpret_cast<const bf16x8*>(&Bs[(wc * 64 + m * 16 + r16) * 64 + kk * 32 + q * 8]);
                }
                #pragma unroll
                for (int m = 0; m < 4; m++)
                    #pragma unroll
                    for (int nn = 0; nn < 4; nn++)
                        acc[m][nn] = __builtin_amdgcn_mfma_f32_16x16x32_bf16(
                            af[m], bfr[nn], acc[m][nn], 0, 0, 0);
            }
        }
        float cw[4], bv[4][4];
        #pragma unroll
        for (int nn = 0; nn < 4; nn++) {
            int t = b * 512 + n0 + wc * 64 + nn * 16 + r16;
            int ev = e01[t];
            cw[nn] = (e == (ev & 255)) ? w0a[t] : ((e == (ev >> 8)) ? w1a[t] : 0.f);
        }
        #pragma unroll
        for (int m = 0; m < 4; m++)
            #pragma unroll
            for (int r = 0; r < 4; r++)
                bv[m][r] = expert_b[e * 1024 + p0 + wr * 64 + m * 16 + q * 4 + r];
        #pragma unroll
        for (int m = 0; m < 4; m++)
            #pragma unroll
            for (int nn = 0; nn < 4; nn++)
                #pragma unroll
                for (int r = 0; r < 4; r++)
                    out_acc[m][nn][r] += cw[nn] * (acc[m][nn][r] + bv[m][r]);
    }
    #pragma unroll
    for (int m = 0; m < 4; m++)
        #pragma unroll
        for (int nn = 0; nn < 4; nn++)
            #pragma unroll
            for (int r = 0; r < 4; r++) {
                int p = p0 + wr * 64 + m * 16 + q * 4 + r;
                int n = n0 + wc * 64 + nn * 16 + r16;
                out[(size_t)b * 1024 * 512 + (size_t)p * 512 + n] = out_acc[m][nn][r];
            }
}

// ---------------------------------------------------------------------------
extern "C" void kernel_launch(void* const* d_in, const int* in_sizes, int n_in,
                              void* d_out, int out_size, void* d_ws, size_t ws_size,
                              hipStream_t stream) {
    const float* x        = (const float*)d_in[0];   // [64][1024][512]
    const float* gate_W   = (const float*)d_in[1];   // [1024][8]
    const float* expert_W = (const float*)d_in[2];   // [8][1024][1024]
    const float* expert_b = (const float*)d_in[3];   // [8][1024]
    float* out = (float*)d_out;                      // [64][1024][512] + [512][8]

    char* ws = (char*)d_ws;
    unsigned short* Wt  = (unsigned short*)(ws + 0);          // 16 MB
    unsigned short* xt  = (unsigned short*)(ws + 16777216);   // 64 MB
    float* gate  = (float*)(ws + 83886080);                   // 1 MB
    float* w0a   = (float*)(ws + 84934656);                   // 128 KB
    float* w1a   = (float*)(ws + 85065728);                   // 128 KB
    int*   e01   = (int*)(ws + 85196800);                     // 128 KB
    int*   hist  = (int*)(ws + 85327872);                     // 8 KB
    int*   coff  = (int*)(ws + 85336064);                     // 8 KB
    int*   meta  = (int*)(ws + 85344256);                     // 256 B
    int*   perm  = (int*)(ws + 85344512);                     // 256 KB
    int*   posA  = (int*)(ws + 85606656);                     // 128 KB
    int*   posB  = (int*)(ws + 85737728);                     // 128 KB
    unsigned short* tmp = (unsigned short*)(ws + 85868800);   // 134.2 MB
    // plog (16 MB) aliases tmp's head: consumed by gate_stage2 before
    // grouped_gemm writes tmp (stream-ordered).
    float* plog = (float*)(ws + 85868800);
    const size_t NEEDED = 85868800ull + 134217728ull;         // ~210 MB

    transpose_cast_kernel<<<dim3(16, 16, 8), 256, 0, stream>>>(expert_W, Wt, 1024, 1024);
    transpose_x_gate_kernel<<<dim3(8, 16, 64), 256, 0, stream>>>(x, gate_W, xt, plog);

    gate_stage2_kernel<<<128, 256, 0, stream>>>(plog, gate, e01, w0a, w1a, hist);
    gate_mean_kernel<<<16, 256, 0, stream>>>(gate, out + 33554432);

    if (ws_size >= NEEDED) {
        scan_kernel<<<1, 256, 0, stream>>>(hist, coff, meta);
        fill_kernel<<<128, 256, 0, stream>>>(e01, coff, perm, posA, posB);
        grouped_gemm_kernel<<<dim3(1088), 512, 0, stream>>>(Wt, xt, perm, meta, expert_b, tmp);
        combine_kernel<<<dim3(8, 8, 64), 256, 0, stream>>>(tmp, posA, posB, w0a, w1a, out);
    } else {
        moe_dense_idx_kernel<<<dim3(4, 8, 64), 256, 0, stream>>>(Wt, xt, e01, w0a, w1a, expert_b, out);
    }
}

// Round 8
// 289.024 us; speedup vs baseline: 1.0918x; 1.0606x over previous
//
#include <hip/hip_runtime.h>
#include <cstddef>

typedef __bf16 bf16x8 __attribute__((ext_vector_type(8)));
typedef float  f32x4  __attribute__((ext_vector_type(4)));
typedef unsigned short u16x8 __attribute__((ext_vector_type(8)));

#define GLOBAL_AS __attribute__((address_space(1)))
#define LDS_AS    __attribute__((address_space(3)))

__device__ __forceinline__ void gload_lds16(const void* g, void* l) {
    __builtin_amdgcn_global_load_lds((const GLOBAL_AS unsigned int*)g,
                                     (LDS_AS unsigned int*)l, 16, 0, 0);
}

__device__ __forceinline__ unsigned short f2bf(float f) {
    union { float f; unsigned int u; } v; v.f = f;
    unsigned int r = v.u + 0x7FFFu + ((v.u >> 16) & 1u);   // RNE
    return (unsigned short)(r >> 16);
}
__device__ __forceinline__ float bf2f(unsigned short h) {
    union { unsigned int u; float f; } v; v.u = ((unsigned int)h) << 16;
    return v.f;
}

// ---------------------------------------------------------------------------
// Transpose + cast (expert_W): src [batch][R][C] f32 -> dst [batch][C][R] bf16
// ---------------------------------------------------------------------------
__global__ __launch_bounds__(256) void transpose_cast_kernel(
    const float* __restrict__ src, unsigned short* __restrict__ dst,
    int R, int C)
{
    const int bat = blockIdx.z;
    src += (size_t)bat * R * C;
    dst += (size_t)bat * R * C;
    const int r0 = blockIdx.y * 64, c0 = blockIdx.x * 64;
    __shared__ float t[64][65];
    const int tid = threadIdx.x;
    const int rr = tid >> 4;
    const int cc = (tid & 15) * 4;

    #pragma unroll
    for (int p = 0; p < 4; p++) {
        int r = p * 16 + rr;
        const float4 v = *reinterpret_cast<const float4*>(&src[(size_t)(r0 + r) * C + c0 + cc]);
        t[r][cc + 0] = v.x; t[r][cc + 1] = v.y; t[r][cc + 2] = v.z; t[r][cc + 3] = v.w;
    }
    __syncthreads();
    #pragma unroll
    for (int p = 0; p < 4; p++) {
        int c = p * 16 + rr;
        ushort4 o;
        o.x = f2bf(t[cc + 0][c]); o.y = f2bf(t[cc + 1][c]);
        o.z = f2bf(t[cc + 2][c]); o.w = f2bf(t[cc + 3][c]);
        *reinterpret_cast<ushort4*>(&dst[(size_t)(c0 + c) * R + r0 + cc]) = o;
    }
}

// ---------------------------------------------------------------------------
// x transpose + fused gate partial-logits.
// ---------------------------------------------------------------------------
__global__ __launch_bounds__(256) void transpose_x_gate_kernel(
    const float* __restrict__ src, const float* __restrict__ gW,
    unsigned short* __restrict__ dst, float* __restrict__ plog)
{
    const int bat = blockIdx.z;
    const int R = 1024, C = 512;
    const float* srcb = src + (size_t)bat * R * C;
    unsigned short* dstb = dst + (size_t)bat * R * C;
    const int r0 = blockIdx.y * 64, c0 = blockIdx.x * 64;
    __shared__ float t[64][65];
    __shared__ float gWs[64][8];
    __shared__ float pacc[4][64][9];
    const int tid = threadIdx.x;
    const int rr = tid >> 4;
    const int cc = (tid & 15) * 4;

    if (tid < 128) {
        reinterpret_cast<float4*>(&gWs[0][0])[tid] =
            reinterpret_cast<const float4*>(gW + (size_t)r0 * 8)[tid];
    }
    #pragma unroll
    for (int p = 0; p < 4; p++) {
        int r = p * 16 + rr;
        const float4 v = *reinterpret_cast<const float4*>(&srcb[(size_t)(r0 + r) * C + c0 + cc]);
        t[r][cc + 0] = v.x; t[r][cc + 1] = v.y; t[r][cc + 2] = v.z; t[r][cc + 3] = v.w;
    }
    __syncthreads();
    #pragma unroll
    for (int p = 0; p < 4; p++) {
        int c = p * 16 + rr;
        ushort4 o;
        o.x = f2bf(t[cc + 0][c]); o.y = f2bf(t[cc + 1][c]);
        o.z = f2bf(t[cc + 2][c]); o.w = f2bf(t[cc + 3][c]);
        *reinterpret_cast<ushort4*>(&dstb[(size_t)(c0 + c) * R + r0 + cc]) = o;
    }

    {
        const int nl = tid & 63;
        const int sc = tid >> 6;
        float a[8];
        #pragma unroll
        for (int e = 0; e < 8; e++) a[e] = 0.f;
        for (int s = sc * 16; s < sc * 16 + 16; s++) {
            float xv = t[s][nl];
            #pragma unroll
            for (int e = 0; e < 8; e++) a[e] = fmaf(xv, gWs[s][e], a[e]);
        }
        #pragma unroll
        for (int e = 0; e < 8; e++) pacc[sc][nl][e] = a[e];
        __syncthreads();
        if (tid < 64) {
            const size_t base = (((size_t)bat * 16 + blockIdx.y) * 512 + c0 + tid) * 8;
            #pragma unroll
            for (int e = 0; e < 8; e++) {
                float v = ((pacc[0][tid][e] + pacc[1][tid][e]) + pacc[2][tid][e]) + pacc[3][tid][e];
                plog[base + e] = v;
            }
        }
    }
}

// ---------------------------------------------------------------------------
// Gate stage 2: reduce partials (fixed order), softmax, top-2, histogram.
// ---------------------------------------------------------------------------
__global__ __launch_bounds__(256) void gate_stage2_kernel(
    const float* __restrict__ plog,
    float* __restrict__ gate, int* __restrict__ e01,
    float* __restrict__ w0a, float* __restrict__ w1a,
    int* __restrict__ hist)
{
    __shared__ int h[16];
    const int tid = threadIdx.x;
    if (tid < 16) h[tid] = 0;
    __syncthreads();

    const int t = blockIdx.x * 256 + tid;
    const int b = t >> 9;
    const int n = t & 511;

    float acc[8];
    #pragma unroll
    for (int e = 0; e < 8; e++) acc[e] = 0.f;
    for (int y = 0; y < 16; y++) {
        const float* pp = plog + (((size_t)b * 16 + y) * 512 + n) * 8;
        const float4 lo = *reinterpret_cast<const float4*>(pp);
        const float4 hi = *reinterpret_cast<const float4*>(pp + 4);
        acc[0] += lo.x; acc[1] += lo.y; acc[2] += lo.z; acc[3] += lo.w;
        acc[4] += hi.x; acc[5] += hi.y; acc[6] += hi.z; acc[7] += hi.w;
    }
    float m = acc[0];
    #pragma unroll
    for (int e = 1; e < 8; e++) m = fmaxf(m, acc[e]);
    float p[8], s = 0.f;
    #pragma unroll
    for (int e = 0; e < 8; e++) { p[e] = __expf(acc[e] - m); s += p[e]; }
    float inv = 1.f / s;
    #pragma unroll
    for (int e = 0; e < 8; e++) p[e] *= inv;

    int e0 = 0;
    #pragma unroll
    for (int e = 1; e < 8; e++) if (p[e] > p[e0]) e0 = e;
    int e1 = -1;
    #pragma unroll
    for (int e = 0; e < 8; e++) {
        if (e == e0) continue;
        if (e1 < 0 || p[e] > p[e1]) e1 = e;
    }

    const size_t base = (size_t)t * 8;
    #pragma unroll
    for (int e = 0; e < 8; e++) gate[base + e] = p[e];
    e01[t] = e0 | (e1 << 8);
    w0a[t] = p[e0];
    w1a[t] = p[e1];

    atomicAdd(&h[e0], 1);
    atomicAdd(&h[8 + e1], 1);
    __syncthreads();
    if (tid < 16) hist[blockIdx.x * 16 + tid] = h[tid];
}

__global__ __launch_bounds__(256) void gate_mean_kernel(
    const float* __restrict__ gate, float* __restrict__ out)
{
    const int idx = blockIdx.x * 256 + threadIdx.x;
    float s = 0.f;
    #pragma unroll 8
    for (int b = 0; b < 64; b++) s += gate[(size_t)b * 4096 + idx];
    out[idx] = s * (1.f / 64.f);
}

// ---------------------------------------------------------------------------
// Scan: hist[128][16] -> chunk_off, meta { base[16], cnt[16], tile_scan[17] }
// tile granularity = 128 tokens (r5 geometry).
// ---------------------------------------------------------------------------
__global__ __launch_bounds__(256) void scan_kernel(
    const int* __restrict__ hist, int* __restrict__ chunk_off,
    int* __restrict__ meta)
{
    __shared__ int cnt_s[16];
    const int tid = threadIdx.x;
    if (tid < 16) {
        int run = 0;
        for (int c = 0; c < 128; c++) {
            chunk_off[c * 16 + tid] = run;
            run += hist[c * 16 + tid];
        }
        cnt_s[tid] = run;
        meta[16 + tid] = run;
    }
    __syncthreads();
    __shared__ int base_s[16];
    if (tid == 0) {
        int run = 0, trun = 0;
        meta[32] = 0;
        for (int g = 0; g < 16; g++) {
            base_s[g] = run;
            meta[g] = run;
            run += cnt_s[g];
            trun += (cnt_s[g] + 127) >> 7;      // 128-token tiles
            meta[33 + g] = trun;
        }
    }
    __syncthreads();
    for (int i = tid; i < 2048; i += 256)
        chunk_off[i] += base_s[i & 15];
}

// ---------------------------------------------------------------------------
// Fill: stable counting-sort placement, ballot-based ranking.
// ---------------------------------------------------------------------------
__global__ __launch_bounds__(256) void fill_kernel(
    const int* __restrict__ e01, const int* __restrict__ chunk_off,
    int* __restrict__ perm, int* __restrict__ posA, int* __restrict__ posB)
{
    __shared__ int wh[4][16];
    const int tid = threadIdx.x;
    const int wv = tid >> 6, lane = tid & 63;
    const int chunk = blockIdx.x;
    const int t = chunk * 256 + tid;
    const int ev = e01[t];
    const int e0 = ev & 255, e1 = ev >> 8;

    const unsigned long long ltmask = (lane == 63) ? 0x7FFFFFFFFFFFFFFFull
                                                   : ((1ull << lane) - 1ull);
    unsigned long long m0sel = 0, m1sel = 0;
    #pragma unroll
    for (int e = 0; e < 8; e++) {
        unsigned long long b0 = __ballot(e0 == e);
        unsigned long long b1 = __ballot(e1 == e);
        if (e0 == e) m0sel = b0;
        if (e1 == e) m1sel = b1;
        if (lane == 0) {
            wh[wv][e]     = __popcll(b0);
            wh[wv][8 + e] = __popcll(b1);
        }
    }
    const int r0l = __popcll(m0sel & ltmask);
    const int r1l = __popcll(m1sel & ltmask);
    __syncthreads();

    int off0 = 0, off1 = 0;
    for (int w = 0; w < wv; w++) { off0 += wh[w][e0]; off1 += wh[w][8 + e1]; }

    const int p0 = chunk_off[chunk * 16 + e0] + off0 + r0l;
    const int p1 = chunk_off[chunk * 16 + 8 + e1] + off1 + r1l;
    perm[p0] = t; perm[p1] = t;
    posA[t] = p0; posB[t] = p1;
}

// ---------------------------------------------------------------------------
// Grouped GEMM: r5 structure (128x128x64, 256 threads, 3 blocks/CU) with
// counted-vmcnt B double-buffer: Bs[2] (LDS 48KB total), raw s_barrier +
// per-wave lgkmcnt(0) (NO vmcnt drain at barriers), B(kt+1) issued before
// compute(kt) and waited with vmcnt(4) -> B HBM latency hidden under a full
// K-tile of MFMA. A single-buffered (L2-warm W). T2 chunk-XOR swizzle
// (0 conflicts, r5-verified). XCD-aware 1D grid (66 tiles x 8 p per XCD).
// ---------------------------------------------------------------------------
__global__ __launch_bounds__(256, 2) void grouped_gemm_kernel(
    const unsigned short* __restrict__ Wt,      // [8][1024 p][1024 s]
    const unsigned short* __restrict__ xt,      // [32768 tok][1024 s]
    const int* __restrict__ perm,
    const int* __restrict__ meta,               // base[16],cnt[16],tile_scan[17]
    const float* __restrict__ expert_b,
    unsigned short* __restrict__ tmp)           // [65536][1024]
{
    const int d   = blockIdx.x;                 // 0..4223
    const int xcd = d & 7;
    const int jj  = d >> 3;
    const int tile = xcd * 66 + (jj >> 3);      // 0..527
    const int p0   = (jj & 7) * 128;

    int g = -1;
    #pragma unroll
    for (int gg = 0; gg < 16; gg++) {
        if (tile >= meta[32 + gg] && tile < meta[33 + gg]) g = gg;
    }
    if (g < 0) return;
    const int lt = tile - meta[32 + g];
    const int e = g & 7;
    const int cnt_local = meta[16 + g] - lt * 128;
    const int pbase = meta[g] + lt * 128;

    __shared__ unsigned short As[128 * 64];     // 16 KB
    __shared__ unsigned short Bs[2][128 * 64];  // 32 KB

    const int tid  = threadIdx.x;
    const int wave = tid >> 6, lane = tid & 63;
    const int wr = wave >> 1, wc = wave & 1;
    const int q = lane >> 4, r16 = lane & 15;
    const int rsw = r16 & 7;

    const int srow   = tid >> 3;                // 0..31
    const int schunk = tid & 7;
    const int gcol   = (schunk ^ (srow & 7)) * 8;   // inverse-swizzled source col

    const unsigned short* Abase = Wt + (size_t)e * 1024 * 1024;

    int tok[4];
    #pragma unroll
    for (int c = 0; c < 4; c++) {
        int row = c * 32 + srow;
        int idx = row < cnt_local ? row : 0;
        tok[c] = perm[pbase + idx];
    }

    f32x4 acc[4][4];
    #pragma unroll
    for (int m = 0; m < 4; m++)
        #pragma unroll
        for (int nn = 0; nn < 4; nn++)
            acc[m][nn] = (f32x4){0.f, 0.f, 0.f, 0.f};

    #define STAGE_A(kt) do {                                                      \
        _Pragma("unroll")                                                         \
        for (int c = 0; c < 4; c++) {                                             \
            int row = c * 32 + srow;                                              \
            gload_lds16(Abase + (size_t)(p0 + row) * 1024 + (kt) * 64 + gcol,     \
                        &As[row * 64 + schunk * 8]);                              \
        } } while (0)
    #define STAGE_B(buf, kt) do {                                                 \
        _Pragma("unroll")                                                         \
        for (int c = 0; c < 4; c++) {                                             \
            int row = c * 32 + srow;                                              \
            gload_lds16(xt + (size_t)tok[c] * 1024 + (kt) * 64 + gcol,            \
                        &Bs[buf][row * 64 + schunk * 8]);                         \
        } } while (0)

    // prologue: B(0) in flight early
    STAGE_B(0, 0);

    for (int kt = 0; kt < 16; kt++) {
        const int cur = kt & 1;
        // protect As/Bs[cur^1 writes]: my ds_reads retired, then block barrier.
        // NOTE: no vmcnt drain here — B loads stay in flight across barrier.
        asm volatile("s_waitcnt lgkmcnt(0)" ::: "memory");
        __builtin_amdgcn_sched_barrier(0);
        __builtin_amdgcn_s_barrier();
        __builtin_amdgcn_sched_barrier(0);

        STAGE_A(kt);                         // overwrite As (all readers done)
        if (kt < 15) STAGE_B(cur ^ 1, kt + 1);
        if (kt < 15) {
            // outstanding: A(kt)=4 + B(kt+1)=4 (+ B(kt) remainder counted out
            // at previous iteration). Wait until 4 remain: A(kt) and B(kt)
            // landed; B(kt+1) still in flight across the compute below.
            asm volatile("s_waitcnt vmcnt(4)" ::: "memory");
        } else {
            asm volatile("s_waitcnt vmcnt(0)" ::: "memory");
        }
        __builtin_amdgcn_sched_barrier(0);
        __builtin_amdgcn_s_barrier();
        __builtin_amdgcn_sched_barrier(0);

        #pragma unroll
        for (int kk = 0; kk < 2; kk++) {
            const int ch = ((kk * 4 + q) ^ rsw) * 8;
            bf16x8 af[4], bfr[4];
            #pragma unroll
            for (int m = 0; m < 4; m++) {
                af[m]  = *reinterpret_cast<const bf16x8*>(&As[(wr * 64 + m * 16 + r16) * 64 + ch]);
                bfr[m] = *reinterpret_cast<const bf16x8*>(&Bs[cur][(wc * 64 + m * 16 + r16) * 64 + ch]);
            }
            #pragma unroll
            for (int m = 0; m < 4; m++)
                #pragma unroll
                for (int nn = 0; nn < 4; nn++)
                    acc[m][nn] = __builtin_amdgcn_mfma_f32_16x16x32_bf16(
                        af[m], bfr[nn], acc[m][nn], 0, 0, 0);
        }
    }
    #undef STAGE_A
    #undef STAGE_B

    float bv[4][4];
    #pragma unroll
    for (int m = 0; m < 4; m++)
        #pragma unroll
        for (int r = 0; r < 4; r++)
            bv[m][r] = expert_b[e * 1024 + p0 + wr * 64 + m * 16 + q * 4 + r];

    #pragma unroll
    for (int nn = 0; nn < 4; nn++) {
        const int j = wc * 64 + nn * 16 + r16;
        if (j < cnt_local) {
            const size_t rowb = (size_t)(pbase + j) * 1024;
            #pragma unroll
            for (int m = 0; m < 4; m++) {
                ushort4 o;
                o.x = f2bf(acc[m][nn][0] + bv[m][0]);
                o.y = f2bf(acc[m][nn][1] + bv[m][1]);
                o.z = f2bf(acc[m][nn][2] + bv[m][2]);
                o.w = f2bf(acc[m][nn][3] + bv[m][3]);
                *reinterpret_cast<ushort4*>(&tmp[rowb + p0 + wr * 64 + m * 16 + q * 4]) = o;
            }
        }
    }
}

// ---------------------------------------------------------------------------
// Combine: out[b,p,n] = w0[t]*tmp[posA[t]][p] + w1[t]*tmp[posB[t]][p]
// ---------------------------------------------------------------------------
__global__ __launch_bounds__(256) void combine_kernel(
    const unsigned short* __restrict__ tmp,
    const int* __restrict__ posA, const int* __restrict__ posB,
    const float* __restrict__ w0a, const float* __restrict__ w1a,
    float* __restrict__ out)
{
    __shared__ unsigned short l0[64 * 128];
    __shared__ unsigned short l1[64 * 128];
    __shared__ float sw0[64], sw1[64];
    const int tid = threadIdx.x;
    const int b = blockIdx.z;
    const int p0 = blockIdx.y * 128;
    const int n0 = blockIdx.x * 64;

    if (tid < 64) {
        int t = b * 512 + n0 + tid;
        sw0[tid] = w0a[t];
        sw1[tid] = w1a[t];
    }

    #pragma unroll
    for (int pass = 0; pass < 8; pass++) {
        int rowid = pass * 16 + (tid >> 4);
        int slot = rowid >> 6, j = rowid & 63;
        int t = b * 512 + n0 + j;
        int pos = slot ? posB[t] : posA[t];
        u16x8 v = *reinterpret_cast<const u16x8*>(&tmp[(size_t)pos * 1024 + p0 + (tid & 15) * 8]);
        unsigned short* dst = slot ? l1 : l0;
        int c0 = (tid & 15) * 8;
        int sw = (j & 31) << 2;
        ushort4 a; a.x = v[0]; a.y = v[1]; a.z = v[2]; a.w = v[3];
        ushort4 bq; bq.x = v[4]; bq.y = v[5]; bq.z = v[6]; bq.w = v[7];
        *reinterpret_cast<ushort4*>(&dst[j * 128 + (c0 ^ sw)]) = a;
        *reinterpret_cast<ushort4*>(&dst[j * 128 + ((c0 + 4) ^ sw)]) = bq;
    }
    __syncthreads();

    const int j = tid & 63;
    const int wv = tid >> 6;
    const float wa = sw0[j], wb = sw1[j];
    const int sw = (j & 31) << 2;
    #pragma unroll 8
    for (int pp = 0; pp < 32; pp++) {
        int p = wv * 32 + pp;
        float v0 = bf2f(l0[j * 128 + (p ^ sw)]);
        float v1 = bf2f(l1[j * 128 + (p ^ sw)]);
        out[((size_t)b * 1024 + p0 + p) * 512 + n0 + j] = wa * v0 + wb * v1;
    }
}

// ---------------------------------------------------------------------------
// Fallback dense kernel (only if ws too small — not expected).
// ---------------------------------------------------------------------------
__global__ __launch_bounds__(256, 2) void moe_dense_idx_kernel(
    const unsigned short* __restrict__ Wt,
    const unsigned short* __restrict__ xt,
    const int* __restrict__ e01,
    const float* __restrict__ w0a, const float* __restrict__ w1a,
    const float* __restrict__ expert_b,
    float* __restrict__ out)
{
    __shared__ unsigned short As[128 * 64];
    __shared__ unsigned short Bs[128 * 64];

    const int tid  = threadIdx.x;
    const int wave = tid >> 6, lane = tid & 63;
    const int wr = wave >> 1, wc = wave & 1;
    const int q = lane >> 4, r16 = lane & 15;
    const int b  = blockIdx.z;
    const int p0 = blockIdx.y * 128;
    const int n0 = blockIdx.x * 128;

    const unsigned short* Bbase = xt + (size_t)b * 512 * 1024;
    const int srow = tid >> 3;
    const int scol = (tid & 7) * 8;

    f32x4 out_acc[4][4];
    #pragma unroll
    for (int m = 0; m < 4; m++)
        #pragma unroll
        for (int nn = 0; nn < 4; nn++)
            out_acc[m][nn] = (f32x4){0.f, 0.f, 0.f, 0.f};

    for (int e = 0; e < 8; e++) {
        const unsigned short* Abase = Wt + (size_t)e * 1024 * 1024;
        f32x4 acc[4][4];
        #pragma unroll
        for (int m = 0; m < 4; m++)
            #pragma unroll
            for (int nn = 0; nn < 4; nn++)
                acc[m][nn] = (f32x4){0.f, 0.f, 0.f, 0.f};

        for (int kt = 0; kt < 16; kt++) {
            __syncthreads();
            #pragma unroll
            for (int c = 0; c < 4; c++) {
                int row = c * 32 + srow;
                gload_lds16(Abase + (size_t)(p0 + row) * 1024 + kt * 64 + scol,
                            &As[row * 64 + scol]);
            }
            #pragma unroll
            for (int c = 0; c < 4; c++) {
                int row = c * 32 + srow;
                gload_lds16(Bbase + (size_t)(n0 + row) * 1024 + kt * 64 + scol,
                            &Bs[row * 64 + scol]);
            }
            __syncthreads();
            #pragma unroll
            for (int kk = 0; kk < 2; kk++) {
                bf16x8 af[4], bfr[4];
                #pragma unroll
                for (int m = 0; m < 4; m++) {
                    af[m]  = *reinterpret_cast<const bf16x8*>(&As[(wr * 64 + m * 16 + r16) * 64 + kk * 32 + q * 8]);
                    bfr[m] = *reinterpret_cast<const bf16x8*>(&Bs[(wc * 64 + m * 16 + r16) * 64 + kk * 32 + q * 8]);
                }
                #pragma unroll
                for (int m = 0; m < 4; m++)
                    #pragma unroll
                    for (int nn = 0; nn < 4; nn++)
                        acc[m][nn] = __builtin_amdgcn_mfma_f32_16x16x32_bf16(
                            af[m], bfr[nn], acc[m][nn], 0, 0, 0);
            }
        }
        float cw[4], bv[4][4];
        #pragma unroll
        for (int nn = 0; nn < 4; nn++) {
            int t = b * 512 + n0 + wc * 64 + nn * 16 + r16;
            int ev = e01[t];
            cw[nn] = (e == (ev & 255)) ? w0a[t] : ((e == (ev >> 8)) ? w1a[t] : 0.f);
        }
        #pragma unroll
        for (int m = 0; m < 4; m++)
            #pragma unroll
            for (int r = 0; r < 4; r++)
                bv[m][r] = expert_b[e * 1024 + p0 + wr * 64 + m * 16 + q * 4 + r];
        #pragma unroll
        for (int m = 0; m < 4; m++)
            #pragma unroll
            for (int nn = 0; nn < 4; nn++)
                #pragma unroll
                for (int r = 0; r < 4; r++)
                    out_acc[m][nn][r] += cw[nn] * (acc[m][nn][r] + bv[m][r]);
    }
    #pragma unroll
    for (int m = 0; m < 4; m++)
        #pragma unroll
        for (int nn = 0; nn < 4; nn++)
            #pragma unroll
            for (int r = 0; r < 4; r++) {
                int p = p0 + wr * 64 + m * 16 + q * 4 + r;
                int n = n0 + wc * 64 + nn * 16 + r16;
                out[(size_t)b * 1024 * 512 + (size_t)p * 512 + n] = out_acc[m][nn][r];
            }
}

// ---------------------------------------------------------------------------
extern "C" void kernel_launch(void* const* d_in, const int* in_sizes, int n_in,
                              void* d_out, int out_size, void* d_ws, size_t ws_size,
                              hipStream_t stream) {
    const float* x        = (const float*)d_in[0];   // [64][1024][512]
    const float* gate_W   = (const float*)d_in[1];   // [1024][8]
    const float* expert_W = (const float*)d_in[2];   // [8][1024][1024]
    const float* expert_b = (const float*)d_in[3];   // [8][1024]
    float* out = (float*)d_out;                      // [64][1024][512] + [512][8]

    char* ws = (char*)d_ws;
    unsigned short* Wt  = (unsigned short*)(ws + 0);          // 16 MB
    unsigned short* xt  = (unsigned short*)(ws + 16777216);   // 64 MB
    float* gate  = (float*)(ws + 83886080);                   // 1 MB
    float* w0a   = (float*)(ws + 84934656);                   // 128 KB
    float* w1a   = (float*)(ws + 85065728);                   // 128 KB
    int*   e01   = (int*)(ws + 85196800);                     // 128 KB
    int*   hist  = (int*)(ws + 85327872);                     // 8 KB
    int*   coff  = (int*)(ws + 85336064);                     // 8 KB
    int*   meta  = (int*)(ws + 85344256);                     // 256 B
    int*   perm  = (int*)(ws + 85344512);                     // 256 KB
    int*   posA  = (int*)(ws + 85606656);                     // 128 KB
    int*   posB  = (int*)(ws + 85737728);                     // 128 KB
    unsigned short* tmp = (unsigned short*)(ws + 85868800);   // 134.2 MB
    // plog (16 MB) aliases tmp's head: consumed by gate_stage2 before
    // grouped_gemm writes tmp (stream-ordered).
    float* plog = (float*)(ws + 85868800);
    const size_t NEEDED = 85868800ull + 134217728ull;         // ~210 MB

    transpose_cast_kernel<<<dim3(16, 16, 8), 256, 0, stream>>>(expert_W, Wt, 1024, 1024);
    transpose_x_gate_kernel<<<dim3(8, 16, 64), 256, 0, stream>>>(x, gate_W, xt, plog);

    gate_stage2_kernel<<<128, 256, 0, stream>>>(plog, gate, e01, w0a, w1a, hist);
    gate_mean_kernel<<<16, 256, 0, stream>>>(gate, out + 33554432);

    if (ws_size >= NEEDED) {
        scan_kernel<<<1, 256, 0, stream>>>(hist, coff, meta);
        fill_kernel<<<128, 256, 0, stream>>>(e01, coff, perm, posA, posB);
        grouped_gemm_kernel<<<dim3(4224), 256, 0, stream>>>(Wt, xt, perm, meta, expert_b, tmp);
        combine_kernel<<<dim3(8, 8, 64), 256, 0, stream>>>(tmp, posA, posB, w0a, w1a, out);
    } else {
        moe_dense_idx_kernel<<<dim3(4, 8, 64), 256, 0, stream>>>(Wt, xt, e01, w0a, w1a, expert_b, out);
    }
}

// Round 9
// 271.615 us; speedup vs baseline: 1.1618x; 1.0641x over previous
//
#include <hip/hip_runtime.h>
#include <cstddef>

typedef __bf16 bf16x8 __attribute__((ext_vector_type(8)));
typedef float  f32x4  __attribute__((ext_vector_type(4)));
typedef unsigned short u16x8 __attribute__((ext_vector_type(8)));

#define GLOBAL_AS __attribute__((address_space(1)))
#define LDS_AS    __attribute__((address_space(3)))

__device__ __forceinline__ void gload_lds16(const void* g, void* l) {
    __builtin_amdgcn_global_load_lds((const GLOBAL_AS unsigned int*)g,
                                     (LDS_AS unsigned int*)l, 16, 0, 0);
}

__device__ __forceinline__ unsigned short f2bf(float f) {
    union { float f; unsigned int u; } v; v.f = f;
    unsigned int r = v.u + 0x7FFFu + ((v.u >> 16) & 1u);   // RNE
    return (unsigned short)(r >> 16);
}
__device__ __forceinline__ float bf2f(unsigned short h) {
    union { unsigned int u; float f; } v; v.u = ((unsigned int)h) << 16;
    return v.f;
}

// ---------------------------------------------------------------------------
// Transpose + cast (expert_W): src [batch][R][C] f32 -> dst [batch][C][R] bf16
// ---------------------------------------------------------------------------
__global__ __launch_bounds__(256) void transpose_cast_kernel(
    const float* __restrict__ src, unsigned short* __restrict__ dst,
    int R, int C)
{
    const int bat = blockIdx.z;
    src += (size_t)bat * R * C;
    dst += (size_t)bat * R * C;
    const int r0 = blockIdx.y * 64, c0 = blockIdx.x * 64;
    __shared__ float t[64][65];
    const int tid = threadIdx.x;
    const int rr = tid >> 4;
    const int cc = (tid & 15) * 4;

    #pragma unroll
    for (int p = 0; p < 4; p++) {
        int r = p * 16 + rr;
        const float4 v = *reinterpret_cast<const float4*>(&src[(size_t)(r0 + r) * C + c0 + cc]);
        t[r][cc + 0] = v.x; t[r][cc + 1] = v.y; t[r][cc + 2] = v.z; t[r][cc + 3] = v.w;
    }
    __syncthreads();
    #pragma unroll
    for (int p = 0; p < 4; p++) {
        int c = p * 16 + rr;
        ushort4 o;
        o.x = f2bf(t[cc + 0][c]); o.y = f2bf(t[cc + 1][c]);
        o.z = f2bf(t[cc + 2][c]); o.w = f2bf(t[cc + 3][c]);
        *reinterpret_cast<ushort4*>(&dst[(size_t)(c0 + c) * R + r0 + cc]) = o;
    }
}

// ---------------------------------------------------------------------------
// x transpose + fused gate partial-logits.
// ---------------------------------------------------------------------------
__global__ __launch_bounds__(256) void transpose_x_gate_kernel(
    const float* __restrict__ src, const float* __restrict__ gW,
    unsigned short* __restrict__ dst, float* __restrict__ plog)
{
    const int bat = blockIdx.z;
    const int R = 1024, C = 512;
    const float* srcb = src + (size_t)bat * R * C;
    unsigned short* dstb = dst + (size_t)bat * R * C;
    const int r0 = blockIdx.y * 64, c0 = blockIdx.x * 64;
    __shared__ float t[64][65];
    __shared__ float gWs[64][8];
    __shared__ float pacc[4][64][9];
    const int tid = threadIdx.x;
    const int rr = tid >> 4;
    const int cc = (tid & 15) * 4;

    if (tid < 128) {
        reinterpret_cast<float4*>(&gWs[0][0])[tid] =
            reinterpret_cast<const float4*>(gW + (size_t)r0 * 8)[tid];
    }
    #pragma unroll
    for (int p = 0; p < 4; p++) {
        int r = p * 16 + rr;
        const float4 v = *reinterpret_cast<const float4*>(&srcb[(size_t)(r0 + r) * C + c0 + cc]);
        t[r][cc + 0] = v.x; t[r][cc + 1] = v.y; t[r][cc + 2] = v.z; t[r][cc + 3] = v.w;
    }
    __syncthreads();
    #pragma unroll
    for (int p = 0; p < 4; p++) {
        int c = p * 16 + rr;
        ushort4 o;
        o.x = f2bf(t[cc + 0][c]); o.y = f2bf(t[cc + 1][c]);
        o.z = f2bf(t[cc + 2][c]); o.w = f2bf(t[cc + 3][c]);
        *reinterpret_cast<ushort4*>(&dstb[(size_t)(c0 + c) * R + r0 + cc]) = o;
    }

    {
        const int nl = tid & 63;
        const int sc = tid >> 6;
        float a[8];
        #pragma unroll
        for (int e = 0; e < 8; e++) a[e] = 0.f;
        for (int s = sc * 16; s < sc * 16 + 16; s++) {
            float xv = t[s][nl];
            #pragma unroll
            for (int e = 0; e < 8; e++) a[e] = fmaf(xv, gWs[s][e], a[e]);
        }
        #pragma unroll
        for (int e = 0; e < 8; e++) pacc[sc][nl][e] = a[e];
        __syncthreads();
        if (tid < 64) {
            const size_t base = (((size_t)bat * 16 + blockIdx.y) * 512 + c0 + tid) * 8;
            #pragma unroll
            for (int e = 0; e < 8; e++) {
                float v = ((pacc[0][tid][e] + pacc[1][tid][e]) + pacc[2][tid][e]) + pacc[3][tid][e];
                plog[base + e] = v;
            }
        }
    }
}

// ---------------------------------------------------------------------------
// Gate stage 2: reduce partials (fixed order), softmax, top-2, histogram.
// ---------------------------------------------------------------------------
__global__ __launch_bounds__(256) void gate_stage2_kernel(
    const float* __restrict__ plog,
    float* __restrict__ gate, int* __restrict__ e01,
    float* __restrict__ w0a, float* __restrict__ w1a,
    int* __restrict__ hist)
{
    __shared__ int h[16];
    const int tid = threadIdx.x;
    if (tid < 16) h[tid] = 0;
    __syncthreads();

    const int t = blockIdx.x * 256 + tid;
    const int b = t >> 9;
    const int n = t & 511;

    float acc[8];
    #pragma unroll
    for (int e = 0; e < 8; e++) acc[e] = 0.f;
    for (int y = 0; y < 16; y++) {
        const float* pp = plog + (((size_t)b * 16 + y) * 512 + n) * 8;
        const float4 lo = *reinterpret_cast<const float4*>(pp);
        const float4 hi = *reinterpret_cast<const float4*>(pp + 4);
        acc[0] += lo.x; acc[1] += lo.y; acc[2] += lo.z; acc[3] += lo.w;
        acc[4] += hi.x; acc[5] += hi.y; acc[6] += hi.z; acc[7] += hi.w;
    }
    float m = acc[0];
    #pragma unroll
    for (int e = 1; e < 8; e++) m = fmaxf(m, acc[e]);
    float p[8], s = 0.f;
    #pragma unroll
    for (int e = 0; e < 8; e++) { p[e] = __expf(acc[e] - m); s += p[e]; }
    float inv = 1.f / s;
    #pragma unroll
    for (int e = 0; e < 8; e++) p[e] *= inv;

    int e0 = 0;
    #pragma unroll
    for (int e = 1; e < 8; e++) if (p[e] > p[e0]) e0 = e;
    int e1 = -1;
    #pragma unroll
    for (int e = 0; e < 8; e++) {
        if (e == e0) continue;
        if (e1 < 0 || p[e] > p[e1]) e1 = e;
    }

    const size_t base = (size_t)t * 8;
    #pragma unroll
    for (int e = 0; e < 8; e++) gate[base + e] = p[e];
    e01[t] = e0 | (e1 << 8);
    w0a[t] = p[e0];
    w1a[t] = p[e1];

    atomicAdd(&h[e0], 1);
    atomicAdd(&h[8 + e1], 1);
    __syncthreads();
    if (tid < 16) hist[blockIdx.x * 16 + tid] = h[tid];
}

__global__ __launch_bounds__(256) void gate_mean_kernel(
    const float* __restrict__ gate, float* __restrict__ out)
{
    const int idx = blockIdx.x * 256 + threadIdx.x;
    float s = 0.f;
    #pragma unroll 8
    for (int b = 0; b < 64; b++) s += gate[(size_t)b * 4096 + idx];
    out[idx] = s * (1.f / 64.f);
}

// ---------------------------------------------------------------------------
// Fill (scan fused): every block recomputes the global scan from hist
// (8 KB, L2-hot), block 0 writes meta {base[16],cnt[16],tile_scan[17]}.
// Stable counting-sort placement via ballot ranking. grid 128, block 256.
// ---------------------------------------------------------------------------
__global__ __launch_bounds__(256) void fill_kernel(
    const int* __restrict__ e01, const int* __restrict__ hist,
    int* __restrict__ perm, int* __restrict__ posA, int* __restrict__ posB,
    int* __restrict__ meta)
{
    __shared__ int wh[4][16];
    __shared__ int cnt_s[16], myoff_s[16], base_s[16];
    const int tid = threadIdx.x;
    const int wv = tid >> 6, lane = tid & 63;
    const int chunk = blockIdx.x;
    const int t = chunk * 256 + tid;
    const int ev = e01[t];
    const int e0 = ev & 255, e1 = ev >> 8;

    // per-bin walk over chunks: total count + this chunk's exclusive offset
    if (tid < 16) {
        int run = 0, mine = 0;
        for (int c = 0; c < 128; c++) {
            if (c == chunk) mine = run;
            run += hist[c * 16 + tid];
        }
        cnt_s[tid] = run;
        myoff_s[tid] = mine;
    }

    // ballot ranking within chunk (all threads participate)
    const unsigned long long ltmask = (lane == 63) ? 0x7FFFFFFFFFFFFFFFull
                                                   : ((1ull << lane) - 1ull);
    unsigned long long m0sel = 0, m1sel = 0;
    #pragma unroll
    for (int e = 0; e < 8; e++) {
        unsigned long long b0 = __ballot(e0 == e);
        unsigned long long b1 = __ballot(e1 == e);
        if (e0 == e) m0sel = b0;
        if (e1 == e) m1sel = b1;
        if (lane == 0) {
            wh[wv][e]     = __popcll(b0);
            wh[wv][8 + e] = __popcll(b1);
        }
    }
    const int r0l = __popcll(m0sel & ltmask);
    const int r1l = __popcll(m1sel & ltmask);
    __syncthreads();

    if (tid == 0) {
        int run = 0;
        for (int g = 0; g < 16; g++) { base_s[g] = run; run += cnt_s[g]; }
    }
    __syncthreads();

    if (chunk == 0 && tid == 0) {
        int trun = 0;
        meta[32] = 0;
        for (int g = 0; g < 16; g++) {
            meta[g] = base_s[g];
            meta[16 + g] = cnt_s[g];
            trun += (cnt_s[g] + 127) >> 7;      // 128-token tiles
            meta[33 + g] = trun;
        }
    }

    int off0 = 0, off1 = 0;
    for (int w = 0; w < wv; w++) { off0 += wh[w][e0]; off1 += wh[w][8 + e1]; }

    const int p0 = base_s[e0] + myoff_s[e0] + off0 + r0l;
    const int p1 = base_s[8 + e1] + myoff_s[8 + e1] + off1 + r1l;
    perm[p0] = t; perm[p1] = t;
    posA[t] = p0; posB[t] = p1;
}

// ---------------------------------------------------------------------------
// Grouped GEMM (r5-exact, best measured: 154 us, 892 TF, 0 bank conflicts):
// 128x128x64 tile, 256 threads, 32 KB LDS (3 blocks/CU), 2-barrier K-loop,
// T2 chunk-XOR swizzle both-sides, XCD-aware 1D grid (66 tiles x 8 p / XCD).
// ---------------------------------------------------------------------------
__global__ __launch_bounds__(256, 2) void grouped_gemm_kernel(
    const unsigned short* __restrict__ Wt,      // [8][1024 p][1024 s]
    const unsigned short* __restrict__ xt,      // [32768 tok][1024 s]
    const int* __restrict__ perm,
    const int* __restrict__ meta,               // base[16],cnt[16],tile_scan[17]
    const float* __restrict__ expert_b,
    unsigned short* __restrict__ tmp)           // [65536][1024]
{
    const int d   = blockIdx.x;
    const int xcd = d & 7;
    const int jj  = d >> 3;
    const int tile = xcd * 66 + (jj >> 3);      // 0..527
    const int p0   = (jj & 7) * 128;

    int g = -1;
    #pragma unroll
    for (int gg = 0; gg < 16; gg++) {
        if (tile >= meta[32 + gg] && tile < meta[33 + gg]) g = gg;
    }
    if (g < 0) return;
    const int lt = tile - meta[32 + g];
    const int e = g & 7;
    const int cnt_local = meta[16 + g] - lt * 128;
    const int pbase = meta[g] + lt * 128;

    __shared__ unsigned short As[128 * 64];
    __shared__ unsigned short Bs[128 * 64];

    const int tid  = threadIdx.x;
    const int wave = tid >> 6, lane = tid & 63;
    const int wr = wave >> 1, wc = wave & 1;
    const int q = lane >> 4, r16 = lane & 15;
    const int rsw = r16 & 7;

    const int srow   = tid >> 3;                // 0..31
    const int schunk = tid & 7;
    const int gcol   = (schunk ^ (srow & 7)) * 8;   // inverse-swizzled source col

    const unsigned short* Abase = Wt + (size_t)e * 1024 * 1024;

    int tok[4];
    #pragma unroll
    for (int c = 0; c < 4; c++) {
        int row = c * 32 + srow;
        int idx = row < cnt_local ? row : 0;
        tok[c] = perm[pbase + idx];
    }

    f32x4 acc[4][4];
    #pragma unroll
    for (int m = 0; m < 4; m++)
        #pragma unroll
        for (int nn = 0; nn < 4; nn++)
            acc[m][nn] = (f32x4){0.f, 0.f, 0.f, 0.f};

    for (int kt = 0; kt < 16; kt++) {
        __syncthreads();   // protect LDS from previous iteration's readers
        #pragma unroll
        for (int c = 0; c < 4; c++) {
            int row = c * 32 + srow;
            gload_lds16(Abase + (size_t)(p0 + row) * 1024 + kt * 64 + gcol,
                        &As[row * 64 + schunk * 8]);
        }
        #pragma unroll
        for (int c = 0; c < 4; c++) {
            int row = c * 32 + srow;
            gload_lds16(xt + (size_t)tok[c] * 1024 + kt * 64 + gcol,
                        &Bs[row * 64 + schunk * 8]);
        }
        __syncthreads();   // drains vmcnt(0): tile ready

        #pragma unroll
        for (int kk = 0; kk < 2; kk++) {
            const int ch = ((kk * 4 + q) ^ rsw) * 8;
            bf16x8 af[4], bfr[4];
            #pragma unroll
            for (int m = 0; m < 4; m++) {
                af[m]  = *reinterpret_cast<const bf16x8*>(&As[(wr * 64 + m * 16 + r16) * 64 + ch]);
                bfr[m] = *reinterpret_cast<const bf16x8*>(&Bs[(wc * 64 + m * 16 + r16) * 64 + ch]);
            }
            #pragma unroll
            for (int m = 0; m < 4; m++)
                #pragma unroll
                for (int nn = 0; nn < 4; nn++)
                    acc[m][nn] = __builtin_amdgcn_mfma_f32_16x16x32_bf16(
                        af[m], bfr[nn], acc[m][nn], 0, 0, 0);
        }
    }

    float bv[4][4];
    #pragma unroll
    for (int m = 0; m < 4; m++)
        #pragma unroll
        for (int r = 0; r < 4; r++)
            bv[m][r] = expert_b[e * 1024 + p0 + wr * 64 + m * 16 + q * 4 + r];

    #pragma unroll
    for (int nn = 0; nn < 4; nn++) {
        const int j = wc * 64 + nn * 16 + r16;
        if (j < cnt_local) {
            const size_t rowb = (size_t)(pbase + j) * 1024;
            #pragma unroll
            for (int m = 0; m < 4; m++) {
                ushort4 o;
                o.x = f2bf(acc[m][nn][0] + bv[m][0]);
                o.y = f2bf(acc[m][nn][1] + bv[m][1]);
                o.z = f2bf(acc[m][nn][2] + bv[m][2]);
                o.w = f2bf(acc[m][nn][3] + bv[m][3]);
                *reinterpret_cast<ushort4*>(&tmp[rowb + p0 + wr * 64 + m * 16 + q * 4]) = o;
            }
        }
    }
}

// ---------------------------------------------------------------------------
// Combine: out[b,p,n] = w0[t]*tmp[posA[t]][p] + w1[t]*tmp[posB[t]][p]
// ---------------------------------------------------------------------------
__global__ __launch_bounds__(256) void combine_kernel(
    const unsigned short* __restrict__ tmp,
    const int* __restrict__ posA, const int* __restrict__ posB,
    const float* __restrict__ w0a, const float* __restrict__ w1a,
    float* __restrict__ out)
{
    __shared__ unsigned short l0[64 * 128];
    __shared__ unsigned short l1[64 * 128];
    __shared__ float sw0[64], sw1[64];
    const int tid = threadIdx.x;
    const int b = blockIdx.z;
    const int p0 = blockIdx.y * 128;
    const int n0 = blockIdx.x * 64;

    if (tid < 64) {
        int t = b * 512 + n0 + tid;
        sw0[tid] = w0a[t];
        sw1[tid] = w1a[t];
    }

    #pragma unroll
    for (int pass = 0; pass < 8; pass++) {
        int rowid = pass * 16 + (tid >> 4);
        int slot = rowid >> 6, j = rowid & 63;
        int t = b * 512 + n0 + j;
        int pos = slot ? posB[t] : posA[t];
        u16x8 v = *reinterpret_cast<const u16x8*>(&tmp[(size_t)pos * 1024 + p0 + (tid & 15) * 8]);
        unsigned short* dst = slot ? l1 : l0;
        int c0 = (tid & 15) * 8;
        int sw = (j & 31) << 2;
        ushort4 a; a.x = v[0]; a.y = v[1]; a.z = v[2]; a.w = v[3];
        ushort4 bq; bq.x = v[4]; bq.y = v[5]; bq.z = v[6]; bq.w = v[7];
        *reinterpret_cast<ushort4*>(&dst[j * 128 + (c0 ^ sw)]) = a;
        *reinterpret_cast<ushort4*>(&dst[j * 128 + ((c0 + 4) ^ sw)]) = bq;
    }
    __syncthreads();

    const int j = tid & 63;
    const int wv = tid >> 6;
    const float wa = sw0[j], wb = sw1[j];
    const int sw = (j & 31) << 2;
    #pragma unroll 8
    for (int pp = 0; pp < 32; pp++) {
        int p = wv * 32 + pp;
        float v0 = bf2f(l0[j * 128 + (p ^ sw)]);
        float v1 = bf2f(l1[j * 128 + (p ^ sw)]);
        out[((size_t)b * 1024 + p0 + p) * 512 + n0 + j] = wa * v0 + wb * v1;
    }
}

// ---------------------------------------------------------------------------
// Fallback dense kernel (only if ws too small — not expected).
// ---------------------------------------------------------------------------
__global__ __launch_bounds__(256, 2) void moe_dense_idx_kernel(
    const unsigned short* __restrict__ Wt,
    const unsigned short* __restrict__ xt,
    const int* __restrict__ e01,
    const float* __restrict__ w0a, const float* __restrict__ w1a,
    const float* __restrict__ expert_b,
    float* __restrict__ out)
{
    __shared__ unsigned short As[128 * 64];
    __shared__ unsigned short Bs[128 * 64];

    const int tid  = threadIdx.x;
    const int wave = tid >> 6, lane = tid & 63;
    const int wr = wave >> 1, wc = wave & 1;
    const int q = lane >> 4, r16 = lane & 15;
    const int b  = blockIdx.z;
    const int p0 = blockIdx.y * 128;
    const int n0 = blockIdx.x * 128;

    const unsigned short* Bbase = xt + (size_t)b * 512 * 1024;
    const int srow = tid >> 3;
    const int scol = (tid & 7) * 8;

    f32x4 out_acc[4][4];
    #pragma unroll
    for (int m = 0; m < 4; m++)
        #pragma unroll
        for (int nn = 0; nn < 4; nn++)
            out_acc[m][nn] = (f32x4){0.f, 0.f, 0.f, 0.f};

    for (int e = 0; e < 8; e++) {
        const unsigned short* Abase = Wt + (size_t)e * 1024 * 1024;
        f32x4 acc[4][4];
        #pragma unroll
        for (int m = 0; m < 4; m++)
            #pragma unroll
            for (int nn = 0; nn < 4; nn++)
                acc[m][nn] = (f32x4){0.f, 0.f, 0.f, 0.f};

        for (int kt = 0; kt < 16; kt++) {
            __syncthreads();
            #pragma unroll
            for (int c = 0; c < 4; c++) {
                int row = c * 32 + srow;
                gload_lds16(Abase + (size_t)(p0 + row) * 1024 + kt * 64 + scol,
                            &As[row * 64 + scol]);
            }
            #pragma unroll
            for (int c = 0; c < 4; c++) {
                int row = c * 32 + srow;
                gload_lds16(Bbase + (size_t)(n0 + row) * 1024 + kt * 64 + scol,
                            &Bs[row * 64 + scol]);
            }
            __syncthreads();
            #pragma unroll
            for (int kk = 0; kk < 2; kk++) {
                bf16x8 af[4], bfr[4];
                #pragma unroll
                for (int m = 0; m < 4; m++) {
                    af[m]  = *reinterpret_cast<const bf16x8*>(&As[(wr * 64 + m * 16 + r16) * 64 + kk * 32 + q * 8]);
                    bfr[m] = *reinterpret_cast<const bf16x8*>(&Bs[(wc * 64 + m * 16 + r16) * 64 + kk * 32 + q * 8]);
                }
                #pragma unroll
                for (int m = 0; m < 4; m++)
                    #pragma unroll
                    for (int nn = 0; nn < 4; nn++)
                        acc[m][nn] = __builtin_amdgcn_mfma_f32_16x16x32_bf16(
                            af[m], bfr[nn], acc[m][nn], 0, 0, 0);
            }
        }
        float cw[4], bv[4][4];
        #pragma unroll
        for (int nn = 0; nn < 4; nn++) {
            int t = b * 512 + n0 + wc * 64 + nn * 16 + r16;
            int ev = e01[t];
            cw[nn] = (e == (ev & 255)) ? w0a[t] : ((e == (ev >> 8)) ? w1a[t] : 0.f);
        }
        #pragma unroll
        for (int m = 0; m < 4; m++)
            #pragma unroll
            for (int r = 0; r < 4; r++)
                bv[m][r] = expert_b[e * 1024 + p0 + wr * 64 + m * 16 + q * 4 + r];
        #pragma unroll
        for (int m = 0; m < 4; m++)
            #pragma unroll
            for (int nn = 0; nn < 4; nn++)
                #pragma unroll
                for (int r = 0; r < 4; r++)
                    out_acc[m][nn][r] += cw[nn] * (acc[m][nn][r] + bv[m][r]);
    }
    #pragma unroll
    for (int m = 0; m < 4; m++)
        #pragma unroll
        for (int nn = 0; nn < 4; nn++)
            #pragma unroll
            for (int r = 0; r < 4; r++) {
                int p = p0 + wr * 64 + m * 16 + q * 4 + r;
                int n = n0 + wc * 64 + nn * 16 + r16;
                out[(size_t)b * 1024 * 512 + (size_t)p * 512 + n] = out_acc[m][nn][r];
            }
}

// ---------------------------------------------------------------------------
extern "C" void kernel_launch(void* const* d_in, const int* in_sizes, int n_in,
                              void* d_out, int out_size, void* d_ws, size_t ws_size,
                              hipStream_t stream) {
    const float* x        = (const float*)d_in[0];   // [64][1024][512]
    const float* gate_W   = (const float*)d_in[1];   // [1024][8]
    const float* expert_W = (const float*)d_in[2];   // [8][1024][1024]
    const float* expert_b = (const float*)d_in[3];   // [8][1024]
    float* out = (float*)d_out;                      // [64][1024][512] + [512][8]

    char* ws = (char*)d_ws;
    unsigned short* Wt  = (unsigned short*)(ws + 0);          // 16 MB
    unsigned short* xt  = (unsigned short*)(ws + 16777216);   // 64 MB
    float* gate  = (float*)(ws + 83886080);                   // 1 MB
    float* w0a   = (float*)(ws + 84934656);                   // 128 KB
    float* w1a   = (float*)(ws + 85065728);                   // 128 KB
    int*   e01   = (int*)(ws + 85196800);                     // 128 KB
    int*   hist  = (int*)(ws + 85327872);                     // 8 KB
    int*   meta  = (int*)(ws + 85344256);                     // 256 B
    int*   perm  = (int*)(ws + 85344512);                     // 256 KB
    int*   posA  = (int*)(ws + 85606656);                     // 128 KB
    int*   posB  = (int*)(ws + 85737728);                     // 128 KB
    unsigned short* tmp = (unsigned short*)(ws + 85868800);   // 134.2 MB
    // plog (16 MB) aliases tmp's head: consumed by gate_stage2 before
    // grouped_gemm writes tmp (stream-ordered).
    float* plog = (float*)(ws + 85868800);
    const size_t NEEDED = 85868800ull + 134217728ull;         // ~210 MB

    transpose_cast_kernel<<<dim3(16, 16, 8), 256, 0, stream>>>(expert_W, Wt, 1024, 1024);
    transpose_x_gate_kernel<<<dim3(8, 16, 64), 256, 0, stream>>>(x, gate_W, xt, plog);

    gate_stage2_kernel<<<128, 256, 0, stream>>>(plog, gate, e01, w0a, w1a, hist);
    gate_mean_kernel<<<16, 256, 0, stream>>>(gate, out + 33554432);

    if (ws_size >= NEEDED) {
        fill_kernel<<<128, 256, 0, stream>>>(e01, hist, perm, posA, posB, meta);
        grouped_gemm_kernel<<<dim3(4224), 256, 0, stream>>>(Wt, xt, perm, meta, expert_b, tmp);
        combine_kernel<<<dim3(8, 8, 64), 256, 0, stream>>>(tmp, posA, posB, w0a, w1a, out);
    } else {
        moe_dense_idx_kernel<<<dim3(4, 8, 64), 256, 0, stream>>>(Wt, xt, e01, w0a, w1a, expert_b, out);
    }
}